// Round 1
// baseline (829.158 us; speedup 1.0000x reference)
//
#include <hip/hip_runtime.h>
#include <cstddef>

// IMUCNN1DEncoder: [32,512,16,6] -> 3x {Conv1d(k=3,same) + BN(eval) + LeakyReLU(0.1)}
//   (6->64->128->256) -> mean over L=16 -> Linear 256->256 -> [32,512,256]
// Round 0: fused fp32 VALU kernel, 4 segments per 256-thread block, activations in LDS.

namespace {

constexpr int kSeg = 4;          // segments per block
constexpr int kThreads = 256;
constexpr int CIN = 6, L = 16;
constexpr int C1 = 64, C2 = 128, C3 = 256, COUT = 256;
constexpr int NSEG = 32 * 512;   // 16384
constexpr float kEps = 1e-5f, kSlope = 0.1f;

// Halo rows: index 0 and 17 are zero pads; payload at [1..16]. Row stride 18 floats
// keeps 8B alignment for float2 LDS reads. +4-float per-seg skew breaks the 4-way
// same-bank conflict between the 4 seg broadcast groups of a wave.
constexpr int XP_STRIDE = CIN * 18;        // 108  (108 % 32 = 12 -> banks distinct)
constexpr int H1_STRIDE = C1 * 18 + 4;     // 1156 (% 32 = 4)
constexpr int H2_STRIDE = C2 * 18 + 4;     // 2308 (% 32 = 4)

__device__ __forceinline__ void load_row18(const float* __restrict__ row, float* r) {
#pragma unroll
    for (int q = 0; q < 9; ++q) {
        float2 t = *(const float2*)(row + 2 * q);
        r[2 * q] = t.x;
        r[2 * q + 1] = t.y;
    }
}

__global__ __launch_bounds__(kThreads, 2)
void imu_encoder_kernel(const float* __restrict__ imu,
                        const float* __restrict__ w1, const float* __restrict__ b1,
                        const float* __restrict__ g1, const float* __restrict__ be1,
                        const float* __restrict__ m1, const float* __restrict__ v1,
                        const float* __restrict__ w2, const float* __restrict__ b2,
                        const float* __restrict__ g2, const float* __restrict__ be2,
                        const float* __restrict__ m2, const float* __restrict__ v2,
                        const float* __restrict__ w3, const float* __restrict__ b3,
                        const float* __restrict__ g3, const float* __restrict__ be3,
                        const float* __restrict__ m3, const float* __restrict__ v3,
                        const float* __restrict__ wp, const float* __restrict__ bp,
                        float* __restrict__ out)
{
    __shared__ float xp[kSeg * XP_STRIDE];     //  1.7 KB
    __shared__ float h1s[kSeg * H1_STRIDE];    // 18.5 KB
    __shared__ float h2s[kSeg * H2_STRIDE];    // 36.9 KB
    __shared__ float pools[kSeg * C3];         //  4.0 KB   (total ~61.2 KB -> 2 blocks/CU)

    const int tid = threadIdx.x;
    const int seg0 = blockIdx.x * kSeg;        // global segment base

    // ---------------- stage 0: zero halos + load/transpose imu ----------------
    for (int z = tid; z < kSeg * CIN; z += kThreads) {
        int s = z / CIN, c = z % CIN;
        xp[s * XP_STRIDE + c * 18 + 0] = 0.f;
        xp[s * XP_STRIDE + c * 18 + 17] = 0.f;
    }
    for (int z = tid; z < kSeg * C1; z += kThreads) {
        int s = z >> 6, i = z & 63;
        h1s[s * H1_STRIDE + i * 18 + 0] = 0.f;
        h1s[s * H1_STRIDE + i * 18 + 17] = 0.f;
    }
    for (int z = tid; z < kSeg * C2; z += kThreads) {
        int s = z >> 7, i = z & 127;
        h2s[s * H2_STRIDE + i * 18 + 0] = 0.f;
        h2s[s * H2_STRIDE + i * 18 + 17] = 0.f;
    }
    // imu flat: [n][l][c]; we want xp[s][c][l+1]
    for (int e = tid; e < kSeg * L * CIN; e += kThreads) {
        int s = e / (L * CIN);
        int rem = e % (L * CIN);
        int l = rem / CIN, c = rem % CIN;
        xp[s * XP_STRIDE + c * 18 + l + 1] = imu[(size_t)(seg0 + s) * (L * CIN) + rem];
    }
    __syncthreads();

    // ---------------- stage 1: conv1 6->64 + BN + LeakyReLU ----------------
    {
        const int o = tid >> 2;   // 0..63
        const int s = tid & 3;
        const float a = g1[o] * rsqrtf(v1[o] + kEps);
        const float bt = fmaf(a, b1[o] - m1[o], be1[o]);
        float acc[L];
#pragma unroll
        for (int l = 0; l < L; ++l) acc[l] = 0.f;
        const float* wr = w1 + o * CIN * 3;
        const float* xr = xp + s * XP_STRIDE;
#pragma unroll
        for (int i = 0; i < CIN; ++i) {
            float k0 = wr[i * 3 + 0], k1 = wr[i * 3 + 1], k2 = wr[i * 3 + 2];
            float r[18];
            load_row18(xr + i * 18, r);
#pragma unroll
            for (int l = 0; l < L; ++l)
                acc[l] = fmaf(k0, r[l], fmaf(k1, r[l + 1], fmaf(k2, r[l + 2], acc[l])));
        }
        float* hw = h1s + s * H1_STRIDE + o * 18;
#pragma unroll
        for (int l = 0; l < L; ++l) {
            float y = fmaf(a, acc[l], bt);
            hw[l + 1] = y > 0.f ? y : kSlope * y;
        }
    }
    __syncthreads();

    // ---------------- stage 2: conv2 64->128 (2 out-ch per thread) ----------------
    {
        const int s = tid & 3;
        const int ob = tid >> 2;  // 0..63
        float alpha[2], beta[2];
        const float* wrow[2];
#pragma unroll
        for (int j = 0; j < 2; ++j) {
            int o = ob + 64 * j;
            float a = g2[o] * rsqrtf(v2[o] + kEps);
            alpha[j] = a;
            beta[j] = fmaf(a, b2[o] - m2[o], be2[o]);
            wrow[j] = w2 + (size_t)o * C1 * 3;
        }
        float acc[2][L];
#pragma unroll
        for (int j = 0; j < 2; ++j)
#pragma unroll
            for (int l = 0; l < L; ++l) acc[j][l] = 0.f;

        const float* hr = h1s + s * H1_STRIDE;
#pragma unroll 2
        for (int i = 0; i < C1; ++i) {
            float r[18];
            load_row18(hr + i * 18, r);
#pragma unroll
            for (int j = 0; j < 2; ++j) {
                float k0 = wrow[j][i * 3 + 0], k1 = wrow[j][i * 3 + 1], k2 = wrow[j][i * 3 + 2];
#pragma unroll
                for (int l = 0; l < L; ++l)
                    acc[j][l] = fmaf(k0, r[l], fmaf(k1, r[l + 1], fmaf(k2, r[l + 2], acc[j][l])));
            }
        }
#pragma unroll
        for (int j = 0; j < 2; ++j) {
            int o = ob + 64 * j;
            float* hw = h2s + s * H2_STRIDE + o * 18;
#pragma unroll
            for (int l = 0; l < L; ++l) {
                float y = fmaf(alpha[j], acc[j][l], beta[j]);
                hw[l + 1] = y > 0.f ? y : kSlope * y;
            }
        }
    }
    __syncthreads();

    // ---------------- stage 3: conv3 128->256 (4 out-ch per thread) + mean pool ----------------
    {
        const int s = tid & 3;
        const int ob = tid >> 2;  // 0..63
        float alpha[4], beta[4];
        const float* wrow[4];
#pragma unroll
        for (int j = 0; j < 4; ++j) {
            int o = ob + 64 * j;
            float a = g3[o] * rsqrtf(v3[o] + kEps);
            alpha[j] = a;
            beta[j] = fmaf(a, b3[o] - m3[o], be3[o]);
            wrow[j] = w3 + (size_t)o * C2 * 3;
        }
        float acc[4][L];
#pragma unroll
        for (int j = 0; j < 4; ++j)
#pragma unroll
            for (int l = 0; l < L; ++l) acc[j][l] = 0.f;

        const float* hr = h2s + s * H2_STRIDE;
#pragma unroll 2
        for (int i = 0; i < C2; ++i) {
            float r[18];
            load_row18(hr + i * 18, r);
#pragma unroll
            for (int j = 0; j < 4; ++j) {
                float k0 = wrow[j][i * 3 + 0], k1 = wrow[j][i * 3 + 1], k2 = wrow[j][i * 3 + 2];
#pragma unroll
                for (int l = 0; l < L; ++l)
                    acc[j][l] = fmaf(k0, r[l], fmaf(k1, r[l + 1], fmaf(k2, r[l + 2], acc[j][l])));
            }
        }
#pragma unroll
        for (int j = 0; j < 4; ++j) {
            float ssum = 0.f;
#pragma unroll
            for (int l = 0; l < L; ++l) {
                float y = fmaf(alpha[j], acc[j][l], beta[j]);
                y = y > 0.f ? y : kSlope * y;
                ssum += y;
            }
            pools[s * C3 + ob + 64 * j] = ssum * (1.f / 16.f);
        }
    }
    __syncthreads();

    // ---------------- stage 4: linear 256->256 (thread = out-ch, loop segs) ----------------
    {
        const int o = tid;  // 0..255
        float accs[kSeg];
        const float bv = bp[o];
#pragma unroll
        for (int s = 0; s < kSeg; ++s) accs[s] = bv;
        const float* wr = wp + (size_t)o * COUT;
        for (int i = 0; i < COUT; i += 4) {
            float4 w4 = *(const float4*)(wr + i);
#pragma unroll
            for (int s = 0; s < kSeg; ++s) {
                const float* pr = pools + s * C3 + i;
                accs[s] = fmaf(w4.x, pr[0], accs[s]);
                accs[s] = fmaf(w4.y, pr[1], accs[s]);
                accs[s] = fmaf(w4.z, pr[2], accs[s]);
                accs[s] = fmaf(w4.w, pr[3], accs[s]);
            }
        }
#pragma unroll
        for (int s = 0; s < kSeg; ++s)
            out[(size_t)(seg0 + s) * COUT + o] = accs[s];
    }
}

}  // namespace

extern "C" void kernel_launch(void* const* d_in, const int* in_sizes, int n_in,
                              void* d_out, int out_size, void* d_ws, size_t ws_size,
                              hipStream_t stream) {
    const float* imu = (const float*)d_in[0];
    const float* w1 = (const float*)d_in[1];
    const float* b1 = (const float*)d_in[2];
    const float* g1 = (const float*)d_in[3];
    const float* be1 = (const float*)d_in[4];
    const float* m1 = (const float*)d_in[5];
    const float* v1 = (const float*)d_in[6];
    const float* w2 = (const float*)d_in[7];
    const float* b2 = (const float*)d_in[8];
    const float* g2 = (const float*)d_in[9];
    const float* be2 = (const float*)d_in[10];
    const float* m2 = (const float*)d_in[11];
    const float* v2 = (const float*)d_in[12];
    const float* w3 = (const float*)d_in[13];
    const float* b3 = (const float*)d_in[14];
    const float* g3 = (const float*)d_in[15];
    const float* be3 = (const float*)d_in[16];
    const float* m3 = (const float*)d_in[17];
    const float* v3 = (const float*)d_in[18];
    const float* wp = (const float*)d_in[19];
    const float* bpv = (const float*)d_in[20];
    float* out = (float*)d_out;

    dim3 grid(NSEG / kSeg);   // 4096 blocks
    dim3 block(kThreads);
    hipLaunchKernelGGL(imu_encoder_kernel, grid, block, 0, stream,
                       imu, w1, b1, g1, be1, m1, v1,
                       w2, b2, g2, be2, m2, v2,
                       w3, b3, g3, be3, m3, v3,
                       wp, bpv, out);
}

// Round 2
// 166.812 us; speedup vs baseline: 4.9706x; 4.9706x over previous
//
#include <hip/hip_runtime.h>
#include <cstdint>
#include <cstddef>

// IMUCNN1DEncoder — MFMA pipeline.
// K0: weight prep (BN fold -> bf16 swizzled LDS-image panels in d_ws)
// K1: conv1 (VALU) -> act1 bf16 [seg][18][64] (halo rows zeroed); zero act2 halos
// K2: conv2 GEMM  M=128 K=3x64  N=262144 -> act2 bf16 [seg][18][128]
// K3: conv3 GEMM  M=256 K=6x64  N=262144 + bias/leaky + pool + linear -> out f32

namespace {

typedef __attribute__((ext_vector_type(8))) short short8;   // 8 bf16 = 4 VGPR (guide §3)
typedef __attribute__((ext_vector_type(4))) float f32x4;

constexpr int NSEG = 32 * 512;          // 16384
constexpr float kEps = 1e-5f;

// d_ws layout (bytes)
constexpr size_t OFF_ACT1 = 0;                              // 16384*18*64*2  = 37,748,736
constexpr size_t OFF_ACT2 = 37748736;                       // 16384*18*128*2 = 75,497,472
constexpr size_t OFF_A2   = OFF_ACT2 + 75497472;            // 3 panels * 16384  = 49,152
constexpr size_t OFF_A3   = OFF_A2 + 49152;                 // 6 panels * 32768  = 196,608
constexpr size_t OFF_WP   = OFF_A3 + 196608;                // 131,072
constexpr size_t OFF_B2   = OFF_WP + 131072;                // 512
constexpr size_t OFF_B3   = OFF_B2 + 512;                   // 1024
constexpr size_t WS_NEED  = OFF_B3 + 1024;                  // ~113.6 MB

__device__ __forceinline__ unsigned short f2bf(float f) {
    union { float f; unsigned int u; } a; a.f = f;
    unsigned int u = a.u + 0x7FFFu + ((a.u >> 16) & 1u);    // RNE
    return (unsigned short)(u >> 16);
}

__device__ __forceinline__ void gll16(const void* g, void* l) {
    __builtin_amdgcn_global_load_lds(
        (const __attribute__((address_space(1))) unsigned int*)g,
        (__attribute__((address_space(3))) unsigned int*)l, 16, 0, 0);
}

__device__ __forceinline__ short8 frag16(const void* p) {
    return __builtin_bit_cast(short8, *(const int4*)p);
}

// ---------------------------------------------------------------- K0: prep
// item ranges: A2 units 3072 | A3 units 12288 | WP units 8192 | b2 128 | b3 256
__global__ __launch_bounds__(256) void k0_prep(
    const float* __restrict__ w2, const float* __restrict__ b2, const float* __restrict__ g2,
    const float* __restrict__ be2, const float* __restrict__ m2, const float* __restrict__ v2,
    const float* __restrict__ w3, const float* __restrict__ b3, const float* __restrict__ g3,
    const float* __restrict__ be3, const float* __restrict__ m3, const float* __restrict__ v3,
    const float* __restrict__ wp, char* __restrict__ ws)
{
    int idx = blockIdx.x * 256 + threadIdx.x;
    if (idx < 3072) {                       // A2: (t, r, q) -> 8 bf16 unit
        int t = idx >> 10, rem = idx & 1023;
        int r = rem >> 3, q = rem & 7;
        float a = g2[r] * rsqrtf(v2[r] + kEps);
        unsigned short us[8];
#pragma unroll
        for (int j = 0; j < 8; ++j) {
            int k = q * 8 + j;              // i = k (0..63)
            us[j] = f2bf(a * w2[r * 192 + k * 3 + t]);
        }
        *(int4*)(ws + OFF_A2 + t * 16384 + r * 128 + ((q ^ (r & 7)) * 16)) = *(const int4*)us;
    } else if (idx < 3072 + 12288) {        // A3
        int u = idx - 3072;
        int t = u >> 11, rem = u & 2047;
        int r = rem >> 3, q = rem & 7;
        int tap = t >> 1, ih = t & 1;
        float a = g3[r] * rsqrtf(v3[r] + kEps);
        unsigned short us[8];
#pragma unroll
        for (int j = 0; j < 8; ++j) {
            int i = ih * 64 + q * 8 + j;
            us[j] = f2bf(a * w3[r * 384 + i * 3 + tap]);
        }
        *(int4*)(ws + OFF_A3 + t * 32768 + r * 128 + ((q ^ (r & 7)) * 16)) = *(const int4*)us;
    } else if (idx < 3072 + 12288 + 8192) { // WP fragment-ordered, scaled by 1/16
        int u = idx - (3072 + 12288);
        int f = u >> 6, lane = u & 63;
        int o = (f >> 3) * 16 + (lane & 15);
        int cb = (f & 7) * 32 + (lane >> 4) * 8;
        unsigned short us[8];
#pragma unroll
        for (int j = 0; j < 8; ++j)
            us[j] = f2bf(wp[o * 256 + cb + j] * 0.0625f);
        *(int4*)(ws + OFF_WP + (size_t)u * 16) = *(const int4*)us;
    } else if (idx < 3072 + 12288 + 8192 + 128) {   // bias2'
        int o = idx - (3072 + 12288 + 8192);
        float a = g2[o] * rsqrtf(v2[o] + kEps);
        ((float*)(ws + OFF_B2))[o] = a * (b2[o] - m2[o]) + be2[o];
    } else if (idx < 3072 + 12288 + 8192 + 128 + 256) {  // bias3'
        int o = idx - (3072 + 12288 + 8192 + 128);
        float a = g3[o] * rsqrtf(v3[o] + kEps);
        ((float*)(ws + OFF_B3))[o] = a * (b3[o] - m3[o]) + be3[o];
    }
}

// ---------------------------------------------------------------- K1: conv1
__global__ __launch_bounds__(256) void k1_conv1(
    const float* __restrict__ imu, const float* __restrict__ w1, const float* __restrict__ b1,
    const float* __restrict__ g1, const float* __restrict__ be1, const float* __restrict__ m1,
    const float* __restrict__ v1, char* __restrict__ ws)
{
    __shared__ __align__(16) float xs[8][16][6];               // 3 KB
    __shared__ __align__(16) unsigned short a1t[8 * 18 * 64];  // 18432 B
    const int tid = threadIdx.x;
    const int seg0 = blockIdx.x * 8;

    const float* src = imu + (size_t)seg0 * 96;
    if (tid < 192) ((float4*)&xs[0][0][0])[tid] = ((const float4*)src)[tid];
    for (int u = tid; u < 8 * 64; u += 256) {
        int s = u >> 6, c = u & 63;
        a1t[(s * 18 + 0) * 64 + c] = 0;
        a1t[(s * 18 + 17) * 64 + c] = 0;
    }
    __syncthreads();

    const int c = tid & 63, sp = tid >> 6;   // sp 0..3
    const float a = g1[c] * rsqrtf(v1[c] + kEps);
    const float bb = fmaf(a, b1[c] - m1[c], be1[c]);
    float wk[6][3];
#pragma unroll
    for (int i = 0; i < 6; ++i)
#pragma unroll
        for (int k = 0; k < 3; ++k) wk[i][k] = a * w1[c * 18 + i * 3 + k];

#pragma unroll
    for (int ss = 0; ss < 2; ++ss) {
        int s = sp + ss * 4;
        float acc[16];
#pragma unroll
        for (int l = 0; l < 16; ++l) acc[l] = bb;
#pragma unroll
        for (int i = 0; i < 6; ++i) {
            float x[16];
#pragma unroll
            for (int l = 0; l < 16; ++l) x[l] = xs[s][l][i];
#pragma unroll
            for (int l = 0; l < 16; ++l) {
                float t = wk[i][1] * x[l];
                if (l > 0)  t = fmaf(wk[i][0], x[l - 1], t);
                if (l < 15) t = fmaf(wk[i][2], x[l + 1], t);
                acc[l] += t;
            }
        }
#pragma unroll
        for (int l = 0; l < 16; ++l) {
            float y = acc[l];
            y = y > 0.f ? y : 0.1f * y;
            a1t[(s * 18 + l + 1) * 64 + c] = f2bf(y);
        }
    }
    __syncthreads();

    char* act1 = ws + OFF_ACT1 + (size_t)seg0 * (18 * 64 * 2);
    for (int u = tid; u < 1152; u += 256)
        ((int4*)act1)[u] = ((const int4*)a1t)[u];

    // zero act2 halos (rows p=0 and p=17) for these 8 segs
    {
        int4 z; z.x = z.y = z.z = z.w = 0;
        int u = tid;
        if (u < 256) {
            int s = u >> 5, rest = u & 31, h = rest >> 4, q = rest & 15;
            size_t byte = ((size_t)(seg0 + s) * 18 + (h ? 17 : 0)) * 256 + q * 16;
            *(int4*)(ws + OFF_ACT2 + byte) = z;
        }
    }
}

// ---------------------------------------------------------------- K2: conv2 GEMM
// LDS: A0 @0 (16K) | A1 @16K | B0 @32K (32K) | B1 @64K ; trans overlays @32K (64K)
__global__ __launch_bounds__(512, 2) void k2_conv2(char* __restrict__ ws)
{
    extern __shared__ char smem[];
    const char* A2img = ws + OFF_A2;
    const char* act1  = ws + OFF_ACT1;
    char* act2        = ws + OFF_ACT2;
    const float* bias2 = (const float*)(ws + OFF_B2);

    const int tid = threadIdx.x, lane = tid & 63, wid = tid >> 6;
    const int seg0 = blockIdx.x * 16;
    const int hi = lane >> 4, lo = lane & 15;

    // B staging source bases (4 issues/wave); +t*128 bytes per tap
    const char* srcB[4];
#pragma unroll
    for (int is = 0; is < 4; ++is) {
        int uB = wid * 256 + is * 64 + lane;
        int col = uB >> 3, qp = uB & 7;
        int q = qp ^ (col & 7);
        int seg = seg0 + (col >> 4), lpos = col & 15;
        srcB[is] = act1 + ((size_t)seg * 18 + lpos) * 128 + q * 16;
    }

    f32x4 acc[4][4];
#pragma unroll
    for (int i = 0; i < 4; ++i)
#pragma unroll
        for (int j = 0; j < 4; ++j) acc[i][j] = f32x4{0.f, 0.f, 0.f, 0.f};

    const int row0 = (wid >> 2) * 64, col0 = (wid & 3) * 64;

    auto stage = [&](int t, int buf) {
        const char* Ab = A2img + t * 16384;
        char* Al = smem + buf * 16384;
#pragma unroll
        for (int is = 0; is < 2; ++is) {
            int u0 = wid * 128 + is * 64;
            gll16(Ab + (u0 + lane) * 16, Al + u0 * 16);
        }
        char* Bl = smem + 32768 + buf * 32768;
#pragma unroll
        for (int is = 0; is < 4; ++is) {
            int u0 = wid * 256 + is * 64;
            gll16(srcB[is] + t * 128, Bl + u0 * 16);
        }
    };
    auto compute = [&](int buf) {
        const char* Al = smem + buf * 16384;
        const char* Bl = smem + 32768 + buf * 32768;
#pragma unroll
        for (int q = 0; q < 2; ++q) {
            const int sw = ((q * 4 + hi) ^ (lo & 7)) * 16;
            short8 bfr[4];
#pragma unroll
            for (int ct = 0; ct < 4; ++ct)
                bfr[ct] = frag16(Bl + (col0 + ct * 16 + lo) * 128 + sw);
#pragma unroll
            for (int rt = 0; rt < 4; ++rt) {
                short8 afr = frag16(Al + (row0 + rt * 16 + lo) * 128 + sw);
#pragma unroll
                for (int ct = 0; ct < 4; ++ct)
                    acc[rt][ct] = __builtin_amdgcn_mfma_f32_16x16x32_bf16(
                        afr, bfr[ct], acc[rt][ct], 0, 0, 0);
            }
        }
    };

    stage(0, 0);
    __syncthreads();
#pragma unroll
    for (int t = 0; t < 3; ++t) {
        if (t < 2) stage(t + 1, (t + 1) & 1);
        compute(t & 1);
        __syncthreads();
    }

    // epilogue: bias + leaky -> bf16 -> LDS transpose -> coalesced act2 write
    char* trans = smem + 32768;
#pragma unroll
    for (int rt = 0; rt < 4; ++rt) {
        int ob = row0 + rt * 16 + hi * 4;
        float4 b4 = *(const float4*)(bias2 + ob);
        float bv[4] = {b4.x, b4.y, b4.z, b4.w};
#pragma unroll
        for (int ct = 0; ct < 4; ++ct) {
            int col = col0 + ct * 16 + lo;
            unsigned int p0, p1;
            {
                float y0 = acc[rt][ct][0] + bv[0]; y0 = y0 > 0.f ? y0 : 0.1f * y0;
                float y1 = acc[rt][ct][1] + bv[1]; y1 = y1 > 0.f ? y1 : 0.1f * y1;
                float y2 = acc[rt][ct][2] + bv[2]; y2 = y2 > 0.f ? y2 : 0.1f * y2;
                float y3 = acc[rt][ct][3] + bv[3]; y3 = y3 > 0.f ? y3 : 0.1f * y3;
                p0 = (unsigned int)f2bf(y0) | ((unsigned int)f2bf(y1) << 16);
                p1 = (unsigned int)f2bf(y2) | ((unsigned int)f2bf(y3) << 16);
            }
            uint2 pk; pk.x = p0; pk.y = p1;
            *(uint2*)(trans + (size_t)col * 256 + ob * 2) = pk;
        }
    }
    __syncthreads();
    for (int u = tid; u < 4096; u += 512) {
        int col = u >> 4, k = u & 15;
        int seg = seg0 + (col >> 4), lpos = col & 15;
        int4 v = ((const int4*)trans)[u];
        *(int4*)(act2 + ((size_t)seg * 18 + lpos + 1) * 256 + k * 16) = v;
    }
}

// ---------------------------------------------------------------- K3: conv3 + pool + linear
// LDS: A0 @0 (32K) | A1 @32K | B0 @64K (32K) | B1 @96K | pools @128K (16*560 B)
__global__ __launch_bounds__(512, 2) void k3_conv3(
    char* __restrict__ ws, const float* __restrict__ bp, float* __restrict__ out)
{
    extern __shared__ char smem[];
    const char* A3img = ws + OFF_A3;
    const char* act2  = ws + OFF_ACT2;
    const char* wpimg = ws + OFF_WP;
    const float* bias3 = (const float*)(ws + OFF_B3);

    const int tid = threadIdx.x, lane = tid & 63, wid = tid >> 6;
    const int seg0 = blockIdx.x * 16;
    const int hi = lane >> 4, lo = lane & 15;

    const char* srcB[4];
#pragma unroll
    for (int is = 0; is < 4; ++is) {
        int uB = wid * 256 + is * 64 + lane;
        int col = uB >> 3, qp = uB & 7;
        int q = qp ^ (col & 7);
        int seg = seg0 + (col >> 4), lpos = col & 15;
        srcB[is] = act2 + ((size_t)seg * 18 + lpos) * 256 + q * 16;
    }

    f32x4 acc[8][4];
#pragma unroll
    for (int i = 0; i < 8; ++i)
#pragma unroll
        for (int j = 0; j < 4; ++j) acc[i][j] = f32x4{0.f, 0.f, 0.f, 0.f};

    const int row0 = (wid >> 2) * 128, col0 = (wid & 3) * 64;

    auto stage = [&](int t, int buf) {
        const char* Ab = A3img + t * 32768;
        char* Al = smem + buf * 32768;
#pragma unroll
        for (int is = 0; is < 4; ++is) {
            int u0 = wid * 256 + is * 64;
            gll16(Ab + (u0 + lane) * 16, Al + u0 * 16);
        }
        char* Bl = smem + 65536 + buf * 32768;
        int tap = t >> 1, ih = t & 1;
        int dB = tap * 256 + ih * 128;
#pragma unroll
        for (int is = 0; is < 4; ++is) {
            int u0 = wid * 256 + is * 64;
            gll16(srcB[is] + dB, Bl + u0 * 16);
        }
    };
    auto compute = [&](int buf) {
        const char* Al = smem + buf * 32768;
        const char* Bl = smem + 65536 + buf * 32768;
#pragma unroll
        for (int q = 0; q < 2; ++q) {
            const int sw = ((q * 4 + hi) ^ (lo & 7)) * 16;
            short8 bfr[4];
#pragma unroll
            for (int ct = 0; ct < 4; ++ct)
                bfr[ct] = frag16(Bl + (col0 + ct * 16 + lo) * 128 + sw);
#pragma unroll
            for (int rt = 0; rt < 8; ++rt) {
                short8 afr = frag16(Al + (row0 + rt * 16 + lo) * 128 + sw);
#pragma unroll
                for (int ct = 0; ct < 4; ++ct)
                    acc[rt][ct] = __builtin_amdgcn_mfma_f32_16x16x32_bf16(
                        afr, bfr[ct], acc[rt][ct], 0, 0, 0);
            }
        }
    };

    stage(0, 0);
    __syncthreads();
#pragma unroll
    for (int t = 0; t < 6; ++t) {
        if (t < 5) stage(t + 1, (t + 1) & 1);
        compute(t & 1);
        __syncthreads();
    }

    // epilogue A: bias + leaky + pool(sum over 16 l) -> bf16 pools[seg][280]
    char* pools = smem + 131072;
#pragma unroll
    for (int rt = 0; rt < 8; ++rt) {
        int ob = row0 + rt * 16 + hi * 4;
        float4 b4 = *(const float4*)(bias3 + ob);
        float bv[4] = {b4.x, b4.y, b4.z, b4.w};
#pragma unroll
        for (int ct = 0; ct < 4; ++ct) {
            int seg = (wid & 3) * 4 + ct;
            float s4[4];
#pragma unroll
            for (int r = 0; r < 4; ++r) {
                float y = acc[rt][ct][r] + bv[r];
                y = y > 0.f ? y : 0.1f * y;
#pragma unroll
                for (int m = 1; m < 16; m <<= 1) y += __shfl_xor(y, m, 64);
                s4[r] = y;
            }
            if (lo == 0) {
                uint2 pk;
                pk.x = (unsigned int)f2bf(s4[0]) | ((unsigned int)f2bf(s4[1]) << 16);
                pk.y = (unsigned int)f2bf(s4[2]) | ((unsigned int)f2bf(s4[3]) << 16);
                *(uint2*)(pools + seg * 560 + ob * 2) = pk;
            }
        }
    }
    __syncthreads();

    // epilogue B: linear 256->256 over the 16 pooled segs (wp/16 folded at prep)
    f32x4 acc2[2];
    acc2[0] = f32x4{0.f, 0.f, 0.f, 0.f};
    acc2[1] = f32x4{0.f, 0.f, 0.f, 0.f};
#pragma unroll
    for (int q = 0; q < 8; ++q) {
        short8 bfr = frag16(pools + lo * 560 + q * 64 + hi * 16);
#pragma unroll
        for (int r2 = 0; r2 < 2; ++r2) {
            int f = (wid * 2 + r2) * 8 + q;
            short8 afr = frag16(wpimg + (size_t)(f * 64 + lane) * 16);
            acc2[r2] = __builtin_amdgcn_mfma_f32_16x16x32_bf16(afr, bfr, acc2[r2], 0, 0, 0);
        }
    }
#pragma unroll
    for (int r2 = 0; r2 < 2; ++r2) {
        int o0 = (wid * 2 + r2) * 16 + hi * 4;
        float4 bp4 = *(const float4*)(bp + o0);
        float4 v;
        v.x = acc2[r2][0] + bp4.x;
        v.y = acc2[r2][1] + bp4.y;
        v.z = acc2[r2][2] + bp4.z;
        v.w = acc2[r2][3] + bp4.w;
        *(float4*)(out + (size_t)(seg0 + lo) * 256 + o0) = v;
    }
}

}  // namespace

extern "C" void kernel_launch(void* const* d_in, const int* in_sizes, int n_in,
                              void* d_out, int out_size, void* d_ws, size_t ws_size,
                              hipStream_t stream) {
    if (ws_size < WS_NEED) return;  // would show as absmax failure -> investigate ws_size

    const float* imu = (const float*)d_in[0];
    const float* w1 = (const float*)d_in[1];  const float* b1 = (const float*)d_in[2];
    const float* g1 = (const float*)d_in[3];  const float* be1 = (const float*)d_in[4];
    const float* m1 = (const float*)d_in[5];  const float* v1 = (const float*)d_in[6];
    const float* w2 = (const float*)d_in[7];  const float* b2 = (const float*)d_in[8];
    const float* g2 = (const float*)d_in[9];  const float* be2 = (const float*)d_in[10];
    const float* m2 = (const float*)d_in[11]; const float* v2 = (const float*)d_in[12];
    const float* w3 = (const float*)d_in[13]; const float* b3 = (const float*)d_in[14];
    const float* g3 = (const float*)d_in[15]; const float* be3 = (const float*)d_in[16];
    const float* m3 = (const float*)d_in[17]; const float* v3 = (const float*)d_in[18];
    const float* wp = (const float*)d_in[19]; const float* bp = (const float*)d_in[20];
    float* out = (float*)d_out;
    char* ws = (char*)d_ws;

    static bool attr_done = false;
    (void)attr_done;
    hipFuncSetAttribute((const void*)k2_conv2,
                        hipFuncAttributeMaxDynamicSharedMemorySize, 98304);
    hipFuncSetAttribute((const void*)k3_conv3,
                        hipFuncAttributeMaxDynamicSharedMemorySize, 140032);

    hipLaunchKernelGGL(k0_prep, dim3(94), dim3(256), 0, stream,
                       w2, b2, g2, be2, m2, v2, w3, b3, g3, be3, m3, v3, wp, ws);
    hipLaunchKernelGGL(k1_conv1, dim3(NSEG / 8), dim3(256), 0, stream,
                       imu, w1, b1, g1, be1, m1, v1, ws);
    hipLaunchKernelGGL(k2_conv2, dim3(NSEG / 16), dim3(512), 98304, stream, ws);
    hipLaunchKernelGGL(k3_conv3, dim3(NSEG / 16), dim3(512), 140032, stream, ws, bp, out);
}

// Round 3
// 166.082 us; speedup vs baseline: 4.9925x; 1.0044x over previous
//
#include <hip/hip_runtime.h>
#include <cstdint>
#include <cstddef>

// IMUCNN1DEncoder — MFMA pipeline, round 3: 64KB-LDS 128x128 tiles, 2 blocks/CU.
// K0: weight prep (BN fold -> bf16 swizzled LDS-image panels in d_ws)
// K1: conv1 (VALU) -> act1 bf16 [seg][18][64]; zero act2 halos
// K2: conv2 GEMM  M=128 K=3x64  N per block=128 (8 segs)
// K3: conv3 GEMM  M=2x128 K=6x64, bias/leaky + pool -> pools bf16 [seg][256]
// K4: linear 256->256 MFMA GEMM + bias -> out f32

namespace {

typedef __attribute__((ext_vector_type(8))) short short8;   // 8 bf16 = 4 VGPR
typedef __attribute__((ext_vector_type(4))) float f32x4;

constexpr int NSEG = 32 * 512;          // 16384
constexpr float kEps = 1e-5f;

// d_ws layout (bytes). pools overlays act1 (act1 dead after K2).
constexpr size_t OFF_ACT1 = 0;                              // 16384*18*64*2  = 37,748,736
constexpr size_t OFF_POOL = 0;                              // 16384*256*2    =  8,388,608
constexpr size_t OFF_ACT2 = 37748736;                       // 16384*18*128*2 = 75,497,472
constexpr size_t OFF_A2   = OFF_ACT2 + 75497472;            // 3 panels * 16384
constexpr size_t OFF_A3   = OFF_A2 + 49152;                 // 6 panels * 32768
constexpr size_t OFF_WP   = OFF_A3 + 196608;                // 131,072
constexpr size_t OFF_B2   = OFF_WP + 131072;                // 512
constexpr size_t OFF_B3   = OFF_B2 + 512;                   // 1024
constexpr size_t WS_NEED  = OFF_B3 + 1024;                  // ~113.6 MB (same as round 2)

__device__ __forceinline__ unsigned short f2bf(float f) {
    union { float f; unsigned int u; } a; a.f = f;
    unsigned int u = a.u + 0x7FFFu + ((a.u >> 16) & 1u);    // RNE
    return (unsigned short)(u >> 16);
}

__device__ __forceinline__ void gll16(const void* g, void* l) {
    __builtin_amdgcn_global_load_lds(
        (const __attribute__((address_space(1))) unsigned int*)g,
        (__attribute__((address_space(3))) unsigned int*)l, 16, 0, 0);
}

__device__ __forceinline__ short8 frag16(const void* p) {
    return __builtin_bit_cast(short8, *(const int4*)p);
}

// ---------------------------------------------------------------- K0: prep
__global__ __launch_bounds__(256) void k0_prep(
    const float* __restrict__ w2, const float* __restrict__ b2, const float* __restrict__ g2,
    const float* __restrict__ be2, const float* __restrict__ m2, const float* __restrict__ v2,
    const float* __restrict__ w3, const float* __restrict__ b3, const float* __restrict__ g3,
    const float* __restrict__ be3, const float* __restrict__ m3, const float* __restrict__ v3,
    const float* __restrict__ wp, char* __restrict__ ws)
{
    int idx = blockIdx.x * 256 + threadIdx.x;
    if (idx < 3072) {                       // A2: (t, r, q)
        int t = idx >> 10, rem = idx & 1023;
        int r = rem >> 3, q = rem & 7;
        float a = g2[r] * rsqrtf(v2[r] + kEps);
        unsigned short us[8];
#pragma unroll
        for (int j = 0; j < 8; ++j) {
            int k = q * 8 + j;
            us[j] = f2bf(a * w2[r * 192 + k * 3 + t]);
        }
        *(int4*)(ws + OFF_A2 + t * 16384 + r * 128 + ((q ^ (r & 7)) * 16)) = *(const int4*)us;
    } else if (idx < 3072 + 12288) {        // A3
        int u = idx - 3072;
        int t = u >> 11, rem = u & 2047;
        int r = rem >> 3, q = rem & 7;
        int tap = t >> 1, ih = t & 1;
        float a = g3[r] * rsqrtf(v3[r] + kEps);
        unsigned short us[8];
#pragma unroll
        for (int j = 0; j < 8; ++j) {
            int i = ih * 64 + q * 8 + j;
            us[j] = f2bf(a * w3[r * 384 + i * 3 + tap]);
        }
        *(int4*)(ws + OFF_A3 + t * 32768 + r * 128 + ((q ^ (r & 7)) * 16)) = *(const int4*)us;
    } else if (idx < 3072 + 12288 + 8192) { // WP fragment-ordered, scaled by 1/16
        int u = idx - (3072 + 12288);
        int f = u >> 6, lane = u & 63;
        int o = (f >> 3) * 16 + (lane & 15);
        int cb = (f & 7) * 32 + (lane >> 4) * 8;
        unsigned short us[8];
#pragma unroll
        for (int j = 0; j < 8; ++j)
            us[j] = f2bf(wp[o * 256 + cb + j] * 0.0625f);
        *(int4*)(ws + OFF_WP + (size_t)u * 16) = *(const int4*)us;
    } else if (idx < 3072 + 12288 + 8192 + 128) {
        int o = idx - (3072 + 12288 + 8192);
        float a = g2[o] * rsqrtf(v2[o] + kEps);
        ((float*)(ws + OFF_B2))[o] = a * (b2[o] - m2[o]) + be2[o];
    } else if (idx < 3072 + 12288 + 8192 + 128 + 256) {
        int o = idx - (3072 + 12288 + 8192 + 128);
        float a = g3[o] * rsqrtf(v3[o] + kEps);
        ((float*)(ws + OFF_B3))[o] = a * (b3[o] - m3[o]) + be3[o];
    }
}

// ---------------------------------------------------------------- K1: conv1
__global__ __launch_bounds__(256) void k1_conv1(
    const float* __restrict__ imu, const float* __restrict__ w1, const float* __restrict__ b1,
    const float* __restrict__ g1, const float* __restrict__ be1, const float* __restrict__ m1,
    const float* __restrict__ v1, char* __restrict__ ws)
{
    __shared__ __align__(16) float xs[8][16][6];
    __shared__ __align__(16) unsigned short a1t[8 * 18 * 64];
    const int tid = threadIdx.x;
    const int seg0 = blockIdx.x * 8;

    const float* src = imu + (size_t)seg0 * 96;
    if (tid < 192) ((float4*)&xs[0][0][0])[tid] = ((const float4*)src)[tid];
    for (int u = tid; u < 8 * 64; u += 256) {
        int s = u >> 6, c = u & 63;
        a1t[(s * 18 + 0) * 64 + c] = 0;
        a1t[(s * 18 + 17) * 64 + c] = 0;
    }
    __syncthreads();

    const int c = tid & 63, sp = tid >> 6;
    const float a = g1[c] * rsqrtf(v1[c] + kEps);
    const float bb = fmaf(a, b1[c] - m1[c], be1[c]);
    float wk[6][3];
#pragma unroll
    for (int i = 0; i < 6; ++i)
#pragma unroll
        for (int k = 0; k < 3; ++k) wk[i][k] = a * w1[c * 18 + i * 3 + k];

#pragma unroll
    for (int ss = 0; ss < 2; ++ss) {
        int s = sp + ss * 4;
        float acc[16];
#pragma unroll
        for (int l = 0; l < 16; ++l) acc[l] = bb;
#pragma unroll
        for (int i = 0; i < 6; ++i) {
            float x[16];
#pragma unroll
            for (int l = 0; l < 16; ++l) x[l] = xs[s][l][i];
#pragma unroll
            for (int l = 0; l < 16; ++l) {
                float t = wk[i][1] * x[l];
                if (l > 0)  t = fmaf(wk[i][0], x[l - 1], t);
                if (l < 15) t = fmaf(wk[i][2], x[l + 1], t);
                acc[l] += t;
            }
        }
#pragma unroll
        for (int l = 0; l < 16; ++l) {
            float y = acc[l];
            y = y > 0.f ? y : 0.1f * y;
            a1t[(s * 18 + l + 1) * 64 + c] = f2bf(y);
        }
    }
    __syncthreads();

    char* act1 = ws + OFF_ACT1 + (size_t)seg0 * (18 * 64 * 2);
    for (int u = tid; u < 1152; u += 256)
        ((int4*)act1)[u] = ((const int4*)a1t)[u];

    {   // zero act2 halo rows (p=0, p=17) for these 8 segs
        int4 z; z.x = z.y = z.z = z.w = 0;
        int u = tid;
        if (u < 256) {
            int s = u >> 5, rest = u & 31, h = rest >> 4, q = rest & 15;
            size_t byte = ((size_t)(seg0 + s) * 18 + (h ? 17 : 0)) * 256 + q * 16;
            *(int4*)(ws + OFF_ACT2 + byte) = z;
        }
    }
}

// ---------------------------------------------------------------- K2: conv2 GEMM 128x128
// LDS 64KB: A0 @0 | A1 @16K | B0 @32K | B1 @48K ; trans (32K) overlays @0
__global__ __launch_bounds__(256, 2) void k2_conv2(char* __restrict__ ws)
{
    __shared__ char smem[65536];
    const char* A2img = ws + OFF_A2;
    const char* act1  = ws + OFF_ACT1;
    char* act2        = ws + OFF_ACT2;
    const float* bias2 = (const float*)(ws + OFF_B2);

    const int tid = threadIdx.x, lane = tid & 63, wid = tid >> 6;
    const int seg0 = blockIdx.x * 8;
    const int hi = lane >> 4, lo = lane & 15;

    const char* srcB[4];
#pragma unroll
    for (int is = 0; is < 4; ++is) {
        int u = wid * 256 + is * 64 + lane;
        int col = u >> 3, qp = u & 7;
        int q = qp ^ (col & 7);
        int seg = seg0 + (col >> 4), lpos = col & 15;
        srcB[is] = act1 + ((size_t)seg * 18 + lpos) * 128 + q * 16;
    }

    f32x4 acc[4][4];
#pragma unroll
    for (int i = 0; i < 4; ++i)
#pragma unroll
        for (int j = 0; j < 4; ++j) acc[i][j] = f32x4{0.f, 0.f, 0.f, 0.f};

    const int row0 = (wid >> 1) * 64, col0 = (wid & 1) * 64;

    auto stage = [&](int t, int buf) {
        const char* Ab = A2img + t * 16384;
        char* Al = smem + buf * 16384;
        char* Bl = smem + 32768 + buf * 16384;
#pragma unroll
        for (int is = 0; is < 4; ++is) {
            int u0 = wid * 256 + is * 64;
            gll16(Ab + (u0 + lane) * 16, Al + u0 * 16);
            gll16(srcB[is] + t * 128, Bl + u0 * 16);
        }
    };
    auto compute = [&](int buf) {
        const char* Al = smem + buf * 16384;
        const char* Bl = smem + 32768 + buf * 16384;
#pragma unroll
        for (int q = 0; q < 2; ++q) {
            const int sw = ((q * 4 + hi) ^ (lo & 7)) * 16;
            short8 bfr[4];
#pragma unroll
            for (int ct = 0; ct < 4; ++ct)
                bfr[ct] = frag16(Bl + (col0 + ct * 16 + lo) * 128 + sw);
#pragma unroll
            for (int rt = 0; rt < 4; ++rt) {
                short8 afr = frag16(Al + (row0 + rt * 16 + lo) * 128 + sw);
#pragma unroll
                for (int ct = 0; ct < 4; ++ct)
                    acc[rt][ct] = __builtin_amdgcn_mfma_f32_16x16x32_bf16(
                        afr, bfr[ct], acc[rt][ct], 0, 0, 0);
            }
        }
    };

    stage(0, 0);
    __syncthreads();
#pragma unroll
    for (int t = 0; t < 3; ++t) {
        if (t < 2) stage(t + 1, (t + 1) & 1);
        compute(t & 1);
        __syncthreads();
    }

    // epilogue: bias + leaky -> bf16 -> swizzled LDS transpose -> coalesced act2 write
    char* trans = smem;   // 128 cols x 256B
#pragma unroll
    for (int rt = 0; rt < 4; ++rt) {
        int ch0 = row0 + rt * 16 + hi * 4;
        float4 b4 = *(const float4*)(bias2 + ch0);
        float bv[4] = {b4.x, b4.y, b4.z, b4.w};
#pragma unroll
        for (int ct = 0; ct < 4; ++ct) {
            int col = col0 + ct * 16 + lo;
            float y0 = acc[rt][ct][0] + bv[0]; y0 = y0 > 0.f ? y0 : 0.1f * y0;
            float y1 = acc[rt][ct][1] + bv[1]; y1 = y1 > 0.f ? y1 : 0.1f * y1;
            float y2 = acc[rt][ct][2] + bv[2]; y2 = y2 > 0.f ? y2 : 0.1f * y2;
            float y3 = acc[rt][ct][3] + bv[3]; y3 = y3 > 0.f ? y3 : 0.1f * y3;
            uint2 pk;
            pk.x = (unsigned int)f2bf(y0) | ((unsigned int)f2bf(y1) << 16);
            pk.y = (unsigned int)f2bf(y2) | ((unsigned int)f2bf(y3) << 16);
            *(uint2*)(trans + col * 256 + ((ch0 * 2) ^ ((col & 7) * 16))) = pk;
        }
    }
    __syncthreads();
    for (int u = tid; u < 2048; u += 256) {
        int col = u >> 4, k = u & 15;
        int seg = seg0 + (col >> 4), lpos = col & 15;
        int4 v = *(const int4*)(trans + col * 256 + ((k ^ (col & 7)) * 16));
        *(int4*)(act2 + ((size_t)seg * 18 + lpos + 1) * 256 + k * 16) = v;
    }
}

// ---------------------------------------------------------------- K3: conv3 GEMM (M split x2) + pool
// LDS 64KB: A0 @0 | A1 @16K | B0 @32K | B1 @48K
__global__ __launch_bounds__(256, 2) void k3_conv3(char* __restrict__ ws)
{
    __shared__ char smem[65536];
    const char* A3img = ws + OFF_A3;
    const char* act2  = ws + OFF_ACT2;
    char* pools       = ws + OFF_POOL;
    const float* bias3 = (const float*)(ws + OFF_B3);

    const int tid = threadIdx.x, lane = tid & 63, wid = tid >> 6;
    const int mh = blockIdx.x & 1;             // M half (paired blocks share B tiles)
    const int seg0 = (blockIdx.x >> 1) * 8;
    const int hi = lane >> 4, lo = lane & 15;

    const char* srcB[4];
#pragma unroll
    for (int is = 0; is < 4; ++is) {
        int u = wid * 256 + is * 64 + lane;
        int col = u >> 3, qp = u & 7;
        int q = qp ^ (col & 7);
        int seg = seg0 + (col >> 4), lpos = col & 15;
        srcB[is] = act2 + ((size_t)seg * 18 + lpos) * 256 + q * 16;
    }

    f32x4 acc[4][4];
#pragma unroll
    for (int i = 0; i < 4; ++i)
#pragma unroll
        for (int j = 0; j < 4; ++j) acc[i][j] = f32x4{0.f, 0.f, 0.f, 0.f};

    const int row0 = (wid >> 1) * 64, col0 = (wid & 1) * 64;

    auto stage = [&](int t, int buf) {
        const char* Ab = A3img + t * 32768 + mh * 16384;
        char* Al = smem + buf * 16384;
        char* Bl = smem + 32768 + buf * 16384;
        int tap = t >> 1, ih = t & 1;
        int dB = tap * 256 + ih * 128;
#pragma unroll
        for (int is = 0; is < 4; ++is) {
            int u0 = wid * 256 + is * 64;
            gll16(Ab + (u0 + lane) * 16, Al + u0 * 16);
            gll16(srcB[is] + dB, Bl + u0 * 16);
        }
    };
    auto compute = [&](int buf) {
        const char* Al = smem + buf * 16384;
        const char* Bl = smem + 32768 + buf * 16384;
#pragma unroll
        for (int q = 0; q < 2; ++q) {
            const int sw = ((q * 4 + hi) ^ (lo & 7)) * 16;
            short8 bfr[4];
#pragma unroll
            for (int ct = 0; ct < 4; ++ct)
                bfr[ct] = frag16(Bl + (col0 + ct * 16 + lo) * 128 + sw);
#pragma unroll
            for (int rt = 0; rt < 4; ++rt) {
                short8 afr = frag16(Al + (row0 + rt * 16 + lo) * 128 + sw);
#pragma unroll
                for (int ct = 0; ct < 4; ++ct)
                    acc[rt][ct] = __builtin_amdgcn_mfma_f32_16x16x32_bf16(
                        afr, bfr[ct], acc[rt][ct], 0, 0, 0);
            }
        }
    };

    stage(0, 0);
    __syncthreads();
#pragma unroll
    for (int t = 0; t < 6; ++t) {
        if (t < 5) stage(t + 1, (t + 1) & 1);
        compute(t & 1);
        __syncthreads();
    }

    // epilogue: bias + leaky + pool(sum over 16 l) -> bf16 pools[seg][256]
#pragma unroll
    for (int rt = 0; rt < 4; ++rt) {
        int ch0 = mh * 128 + row0 + rt * 16 + hi * 4;
        float4 b4 = *(const float4*)(bias3 + ch0);
        float bv[4] = {b4.x, b4.y, b4.z, b4.w};
#pragma unroll
        for (int ct = 0; ct < 4; ++ct) {
            int s = (wid & 1) * 4 + ct;
            float s4[4];
#pragma unroll
            for (int r = 0; r < 4; ++r) {
                float y = acc[rt][ct][r] + bv[r];
                y = y > 0.f ? y : 0.1f * y;
#pragma unroll
                for (int m = 1; m < 16; m <<= 1) y += __shfl_xor(y, m, 64);
                s4[r] = y;
            }
            if (lo == 0) {
                uint2 pk;
                pk.x = (unsigned int)f2bf(s4[0]) | ((unsigned int)f2bf(s4[1]) << 16);
                pk.y = (unsigned int)f2bf(s4[2]) | ((unsigned int)f2bf(s4[3]) << 16);
                *(uint2*)(pools + ((size_t)(seg0 + s) * 256 + ch0) * 2) = pk;
            }
        }
    }
}

// ---------------------------------------------------------------- K4: linear 256->256
__global__ __launch_bounds__(256, 2) void k4_linear(
    const char* __restrict__ ws, const float* __restrict__ bp, float* __restrict__ out)
{
    __shared__ char ps[16384];                 // 32 segs x 256ch bf16, swizzled
    const char* pools = ws + OFF_POOL;
    const char* wpimg = ws + OFF_WP;

    const int tid = threadIdx.x, lane = tid & 63, wid = tid >> 6;
    const int seg0 = blockIdx.x * 32;
    const int hi = lane >> 4, lo = lane & 15;

#pragma unroll
    for (int is = 0; is < 4; ++is) {
        int u = wid * 256 + is * 64 + lane;    // 0..1023
        int seg = u >> 5, j = u & 31;
        gll16(pools + (size_t)(seg0 + seg) * 512 + ((j ^ (seg & 7)) * 16),
              ps + (wid * 256 + is * 64) * 16);
    }
    __syncthreads();

    f32x4 acc[4][2];
#pragma unroll
    for (int i = 0; i < 4; ++i) {
        acc[i][0] = f32x4{0.f, 0.f, 0.f, 0.f};
        acc[i][1] = f32x4{0.f, 0.f, 0.f, 0.f};
    }

#pragma unroll
    for (int q = 0; q < 8; ++q) {
        short8 bfr[2];
#pragma unroll
        for (int ct = 0; ct < 2; ++ct) {
            int seg = ct * 16 + lo;
            bfr[ct] = frag16(ps + seg * 512 + (((q * 4 + hi) ^ (seg & 7)) * 16));
        }
#pragma unroll
        for (int rt = 0; rt < 4; ++rt) {
            short8 afr = frag16(wpimg + (size_t)(((wid * 4 + rt) * 8 + q) * 64 + lane) * 16);
            acc[rt][0] = __builtin_amdgcn_mfma_f32_16x16x32_bf16(afr, bfr[0], acc[rt][0], 0, 0, 0);
            acc[rt][1] = __builtin_amdgcn_mfma_f32_16x16x32_bf16(afr, bfr[1], acc[rt][1], 0, 0, 0);
        }
    }

#pragma unroll
    for (int rt = 0; rt < 4; ++rt) {
        int ch0 = wid * 64 + rt * 16 + hi * 4;
        float4 b4 = *(const float4*)(bp + ch0);
#pragma unroll
        for (int ct = 0; ct < 2; ++ct) {
            int segl = ct * 16 + lo;
            float4 v;
            v.x = acc[rt][ct][0] + b4.x;
            v.y = acc[rt][ct][1] + b4.y;
            v.z = acc[rt][ct][2] + b4.z;
            v.w = acc[rt][ct][3] + b4.w;
            *(float4*)(out + (size_t)(seg0 + segl) * 256 + ch0) = v;
        }
    }
}

}  // namespace

extern "C" void kernel_launch(void* const* d_in, const int* in_sizes, int n_in,
                              void* d_out, int out_size, void* d_ws, size_t ws_size,
                              hipStream_t stream) {
    if (ws_size < WS_NEED) return;

    const float* imu = (const float*)d_in[0];
    const float* w1 = (const float*)d_in[1];  const float* b1 = (const float*)d_in[2];
    const float* g1 = (const float*)d_in[3];  const float* be1 = (const float*)d_in[4];
    const float* m1 = (const float*)d_in[5];  const float* v1 = (const float*)d_in[6];
    const float* w2 = (const float*)d_in[7];  const float* b2 = (const float*)d_in[8];
    const float* g2 = (const float*)d_in[9];  const float* be2 = (const float*)d_in[10];
    const float* m2 = (const float*)d_in[11]; const float* v2 = (const float*)d_in[12];
    const float* w3 = (const float*)d_in[13]; const float* b3 = (const float*)d_in[14];
    const float* g3 = (const float*)d_in[15]; const float* be3 = (const float*)d_in[16];
    const float* m3 = (const float*)d_in[17]; const float* v3 = (const float*)d_in[18];
    const float* wp = (const float*)d_in[19]; const float* bp = (const float*)d_in[20];
    float* out = (float*)d_out;
    char* ws = (char*)d_ws;

    hipLaunchKernelGGL(k0_prep, dim3(94), dim3(256), 0, stream,
                       w2, b2, g2, be2, m2, v2, w3, b3, g3, be3, m3, v3, wp, ws);
    hipLaunchKernelGGL(k1_conv1, dim3(NSEG / 8), dim3(256), 0, stream,
                       imu, w1, b1, g1, be1, m1, v1, ws);
    hipLaunchKernelGGL(k2_conv2, dim3(NSEG / 8), dim3(256), 0, stream, ws);
    hipLaunchKernelGGL(k3_conv3, dim3(NSEG / 4), dim3(256), 0, stream, ws);  // 2 M-halves x 2048
    hipLaunchKernelGGL(k4_linear, dim3(NSEG / 32), dim3(256), 0, stream, ws, bp, out);
}

// Round 4
// 138.331 us; speedup vs baseline: 5.9940x; 1.2006x over previous
//
#include <hip/hip_runtime.h>
#include <cstdint>
#include <cstddef>

// IMUCNN1DEncoder — round 4: fully fused conv pipeline.
// K0:  weight prep (BN fold -> bf16 swizzled LDS-image panels in d_ws)   [unchanged]
// K123: ONE kernel per 16 segs: conv1 (VALU) -> act1 in LDS -> conv2 (pure-LDS GEMM)
//       -> act2 in LDS -> conv3 (A3 double-buffered, B from LDS) -> pool -> pools global
// K4:  linear 256->256 MFMA GEMM + bias -> out f32                        [unchanged]

namespace {

typedef __attribute__((ext_vector_type(8))) short short8;   // 8 bf16 = 4 VGPR
typedef __attribute__((ext_vector_type(4))) float f32x4;

constexpr int NSEG = 32 * 512;          // 16384
constexpr float kEps = 1e-5f;

// d_ws layout (bytes)
constexpr size_t OFF_POOL = 0;                              // 16384*256*2 = 8,388,608
constexpr size_t OFF_A2   = 37748736 + 75497472;            // 3 panels * 16384
constexpr size_t OFF_A3   = OFF_A2 + 49152;                 // 6 panels * 32768
constexpr size_t OFF_WP   = OFF_A3 + 196608;                // 131,072
constexpr size_t OFF_B2   = OFF_WP + 131072;                // 512
constexpr size_t OFF_B3   = OFF_B2 + 512;                   // 1024
constexpr size_t WS_NEED  = OFF_B3 + 1024;

// k123 LDS layout (dynamic, 159744 B total):
//   act1  @ 0      : 16 segs x 18 rows x 128 B (64ch bf16)   = 36,864
//   A2    @ 36864  : 3 panels x 16,384                        = 49,152
//   act2  @ 86016  : 16 segs x 18 rows x 256 B (128ch bf16)  = 73,728
//   A3 dbuf overlays [0, 65536) after conv2; imu scratch overlays act2 head.
constexpr int LDS_A2   = 36864;
constexpr int LDS_ACT2 = 86016;
constexpr int LDS_TOTAL = 159744;

__device__ __forceinline__ unsigned short f2bf(float f) {
    union { float f; unsigned int u; } a; a.f = f;
    unsigned int u = a.u + 0x7FFFu + ((a.u >> 16) & 1u);    // RNE
    return (unsigned short)(u >> 16);
}

__device__ __forceinline__ void gll16(const void* g, void* l) {
    __builtin_amdgcn_global_load_lds(
        (const __attribute__((address_space(1))) unsigned int*)g,
        (__attribute__((address_space(3))) unsigned int*)l, 16, 0, 0);
}

__device__ __forceinline__ short8 frag16(const void* p) {
    return __builtin_bit_cast(short8, *(const int4*)p);
}

// ---------------------------------------------------------------- K0: prep (unchanged)
__global__ __launch_bounds__(256) void k0_prep(
    const float* __restrict__ w2, const float* __restrict__ b2, const float* __restrict__ g2,
    const float* __restrict__ be2, const float* __restrict__ m2, const float* __restrict__ v2,
    const float* __restrict__ w3, const float* __restrict__ b3, const float* __restrict__ g3,
    const float* __restrict__ be3, const float* __restrict__ m3, const float* __restrict__ v3,
    const float* __restrict__ wp, char* __restrict__ ws)
{
    int idx = blockIdx.x * 256 + threadIdx.x;
    if (idx < 3072) {                       // A2: (t, r, q)
        int t = idx >> 10, rem = idx & 1023;
        int r = rem >> 3, q = rem & 7;
        float a = g2[r] * rsqrtf(v2[r] + kEps);
        unsigned short us[8];
#pragma unroll
        for (int j = 0; j < 8; ++j) {
            int k = q * 8 + j;
            us[j] = f2bf(a * w2[r * 192 + k * 3 + t]);
        }
        *(int4*)(ws + OFF_A2 + t * 16384 + r * 128 + ((q ^ (r & 7)) * 16)) = *(const int4*)us;
    } else if (idx < 3072 + 12288) {        // A3
        int u = idx - 3072;
        int t = u >> 11, rem = u & 2047;
        int r = rem >> 3, q = rem & 7;
        int tap = t >> 1, ih = t & 1;
        float a = g3[r] * rsqrtf(v3[r] + kEps);
        unsigned short us[8];
#pragma unroll
        for (int j = 0; j < 8; ++j) {
            int i = ih * 64 + q * 8 + j;
            us[j] = f2bf(a * w3[r * 384 + i * 3 + tap]);
        }
        *(int4*)(ws + OFF_A3 + t * 32768 + r * 128 + ((q ^ (r & 7)) * 16)) = *(const int4*)us;
    } else if (idx < 3072 + 12288 + 8192) { // WP fragment-ordered, scaled by 1/16
        int u = idx - (3072 + 12288);
        int f = u >> 6, lane = u & 63;
        int o = (f >> 3) * 16 + (lane & 15);
        int cb = (f & 7) * 32 + (lane >> 4) * 8;
        unsigned short us[8];
#pragma unroll
        for (int j = 0; j < 8; ++j)
            us[j] = f2bf(wp[o * 256 + cb + j] * 0.0625f);
        *(int4*)(ws + OFF_WP + (size_t)u * 16) = *(const int4*)us;
    } else if (idx < 3072 + 12288 + 8192 + 128) {
        int o = idx - (3072 + 12288 + 8192);
        float a = g2[o] * rsqrtf(v2[o] + kEps);
        ((float*)(ws + OFF_B2))[o] = a * (b2[o] - m2[o]) + be2[o];
    } else if (idx < 3072 + 12288 + 8192 + 128 + 256) {
        int o = idx - (3072 + 12288 + 8192 + 128);
        float a = g3[o] * rsqrtf(v3[o] + kEps);
        ((float*)(ws + OFF_B3))[o] = a * (b3[o] - m3[o]) + be3[o];
    }
}

// ---------------------------------------------------------------- K123: fused conv pipeline
__global__ __launch_bounds__(512, 2) void k123_fused(
    const float* __restrict__ imu,
    const float* __restrict__ w1, const float* __restrict__ b1,
    const float* __restrict__ g1, const float* __restrict__ be1,
    const float* __restrict__ m1, const float* __restrict__ v1,
    char* __restrict__ ws)
{
    extern __shared__ char smem[];
    char* act1L = smem;
    char* a2L   = smem + LDS_A2;
    char* act2L = smem + LDS_ACT2;
    char* imuL  = smem + LDS_ACT2;               // scratch, dead before conv2 epilogue
    const char* A3img = ws + OFF_A3;
    const float* bias2 = (const float*)(ws + OFF_B2);
    const float* bias3 = (const float*)(ws + OFF_B3);
    char* pools = ws + OFF_POOL;

    const int tid = threadIdx.x, lane = tid & 63, wid = tid >> 6;
    const int hi = lane >> 4, lo = lane & 15;
    const int seg0 = blockIdx.x * 16;
    const int rh = wid >> 2, cq = wid & 3;       // wave -> (row-half, col-quarter)

    // ---- phase 0: issue imu (6 KB) + A2 (48 KB) loads; wait imu only
    {
        const char* ig = (const char*)imu + (size_t)seg0 * 384;
        if (wid < 6) gll16(ig + wid * 1024 + lane * 16, imuL + wid * 1024);
        const char* A2img = ws + OFF_A2;
#pragma unroll
        for (int is = 0; is < 6; ++is) {
            int u0 = wid * 6144 + is * 1024;
            gll16(A2img + u0 + lane * 16, a2L + u0);
        }
        asm volatile("s_waitcnt vmcnt(6)\n\ts_barrier" ::: "memory");
    }

    // ---- phase 1: conv1 (VALU) -> act1 in LDS (swizzled rows), A2 lands meanwhile
    {
        const float* xf = (const float*)imuL;
        const int c = tid & 63, sp = tid >> 6;   // 8 sp values, segs sp and sp+8
        const float a = g1[c] * rsqrtf(v1[c] + kEps);
        const float bb = fmaf(a, b1[c] - m1[c], be1[c]);
        float wk[6][3];
#pragma unroll
        for (int i = 0; i < 6; ++i)
#pragma unroll
            for (int k = 0; k < 3; ++k) wk[i][k] = a * w1[c * 18 + i * 3 + k];

#pragma unroll
        for (int ss = 0; ss < 2; ++ss) {
            int s = sp + ss * 8;
            float acc[16];
#pragma unroll
            for (int l = 0; l < 16; ++l) acc[l] = bb;
#pragma unroll
            for (int i = 0; i < 6; ++i) {
                float x[16];
#pragma unroll
                for (int l = 0; l < 16; ++l) x[l] = xf[s * 96 + l * 6 + i];
#pragma unroll
                for (int l = 0; l < 16; ++l) {
                    float t = wk[i][1] * x[l];
                    if (l > 0)  t = fmaf(wk[i][0], x[l - 1], t);
                    if (l < 15) t = fmaf(wk[i][2], x[l + 1], t);
                    acc[l] += t;
                }
            }
#pragma unroll
            for (int l = 0; l < 16; ++l) {
                float y = acc[l];
                y = y > 0.f ? y : 0.1f * y;
                int r = s * 18 + l + 1;
                *(unsigned short*)(act1L + r * 128 + (((c >> 3) ^ (r & 7)) * 16)
                                   + (c & 7) * 2) = f2bf(y);
            }
        }
        if (tid < 256) {                         // zero act1 halo rows p=0,17
            int rr = tid >> 3, unit = tid & 7;
            int s = rr >> 1, p = (rr & 1) * 17;
            int4 z; z.x = z.y = z.z = z.w = 0;
            *(int4*)(act1L + (s * 18 + p) * 128 + unit * 16) = z;
        }
    }
    __syncthreads();                             // act1 + A2 ready (drains vmcnt too)

    // ---- phase 2: conv2 pure-LDS GEMM  M=128 K=3x64 N=256
    f32x4 acc2[4][4];
#pragma unroll
    for (int i = 0; i < 4; ++i)
#pragma unroll
        for (int j = 0; j < 4; ++j) acc2[i][j] = f32x4{0.f, 0.f, 0.f, 0.f};

#pragma unroll
    for (int tap = 0; tap < 3; ++tap) {
#pragma unroll
        for (int qq = 0; qq < 2; ++qq) {
            short8 bfr[4];
#pragma unroll
            for (int ct = 0; ct < 4; ++ct) {
                int r = (cq * 4 + ct) * 18 + lo + tap;
                bfr[ct] = frag16(act1L + r * 128 + (((qq * 4 + hi) ^ (r & 7)) * 16));
            }
#pragma unroll
            for (int rt = 0; rt < 4; ++rt) {
                int ra = rh * 64 + rt * 16 + lo;
                short8 afr = frag16(a2L + tap * 16384 + ra * 128
                                    + (((qq * 4 + hi) ^ (lo & 7)) * 16));
#pragma unroll
                for (int ct = 0; ct < 4; ++ct)
                    acc2[rt][ct] = __builtin_amdgcn_mfma_f32_16x16x32_bf16(
                        afr, bfr[ct], acc2[rt][ct], 0, 0, 0);
            }
        }
    }
    __syncthreads();                             // act1/A2 dead now

    // ---- phase 3: issue A3 stage 0 (into dead act1/A2 region), conv2 epilogue under it
    auto stageA3 = [&](int t, int buf) {
#pragma unroll
        for (int is = 0; is < 4; ++is) {
            int u0 = is * 8192 + wid * 1024;
            gll16(A3img + t * 32768 + u0 + lane * 16, smem + buf * 32768 + u0);
        }
    };
    stageA3(0, 0);
    {
#pragma unroll
        for (int rt = 0; rt < 4; ++rt) {
            int ch0 = rh * 64 + rt * 16 + hi * 4;
            float4 b4 = *(const float4*)(bias2 + ch0);
            float bv[4] = {b4.x, b4.y, b4.z, b4.w};
#pragma unroll
            for (int ct = 0; ct < 4; ++ct) {
                int r = (cq * 4 + ct) * 18 + lo + 1;
                float y0 = acc2[rt][ct][0] + bv[0]; y0 = y0 > 0.f ? y0 : 0.1f * y0;
                float y1 = acc2[rt][ct][1] + bv[1]; y1 = y1 > 0.f ? y1 : 0.1f * y1;
                float y2 = acc2[rt][ct][2] + bv[2]; y2 = y2 > 0.f ? y2 : 0.1f * y2;
                float y3 = acc2[rt][ct][3] + bv[3]; y3 = y3 > 0.f ? y3 : 0.1f * y3;
                uint2 pk;
                pk.x = (unsigned int)f2bf(y0) | ((unsigned int)f2bf(y1) << 16);
                pk.y = (unsigned int)f2bf(y2) | ((unsigned int)f2bf(y3) << 16);
                *(uint2*)(act2L + r * 256 + ((ch0 * 2) ^ ((r & 15) * 16))) = pk;
            }
        }
        {                                        // zero act2 halo rows p=0,17
            int rr = tid >> 4, unit = tid & 15;
            int s = rr >> 1, p = (rr & 1) * 17;
            int4 z; z.x = z.y = z.z = z.w = 0;
            *(int4*)(act2L + (s * 18 + p) * 256 + unit * 16) = z;
        }
    }
    __syncthreads();                             // act2 visible + A3 stage 0 landed

    // ---- phase 4: conv3  M=256 K=6x64 N=256, A3 double-buffered issue-early
    f32x4 acc3[8][4];
#pragma unroll
    for (int i = 0; i < 8; ++i)
#pragma unroll
        for (int j = 0; j < 4; ++j) acc3[i][j] = f32x4{0.f, 0.f, 0.f, 0.f};

#pragma unroll
    for (int t = 0; t < 6; ++t) {
        if (t < 5) stageA3(t + 1, (t + 1) & 1);  // lands under this tile's compute
        const char* Al = smem + (t & 1) * 32768;
        const int tap = t >> 1, ih = t & 1;
#pragma unroll
        for (int qq = 0; qq < 2; ++qq) {
            short8 bfr[4];
#pragma unroll
            for (int ct = 0; ct < 4; ++ct) {
                int r = (cq * 4 + ct) * 18 + lo + tap;
                int u = ih * 8 + qq * 4 + hi;
                bfr[ct] = frag16(act2L + r * 256 + ((u ^ (r & 15)) * 16));
            }
#pragma unroll
            for (int rt = 0; rt < 8; ++rt) {
                int ra = rh * 128 + rt * 16 + lo;
                short8 afr = frag16(Al + ra * 128 + (((qq * 4 + hi) ^ (lo & 7)) * 16));
#pragma unroll
                for (int ct = 0; ct < 4; ++ct)
                    acc3[rt][ct] = __builtin_amdgcn_mfma_f32_16x16x32_bf16(
                        afr, bfr[ct], acc3[rt][ct], 0, 0, 0);
            }
        }
        __syncthreads();                         // drains next stage's loads + read fences
    }

    // ---- phase 5: bias + leaky + pool(sum over 16 l) -> bf16 pools[seg][256] (global)
#pragma unroll
    for (int rt = 0; rt < 8; ++rt) {
        int ch0 = rh * 128 + rt * 16 + hi * 4;
        float4 b4 = *(const float4*)(bias3 + ch0);
        float bv[4] = {b4.x, b4.y, b4.z, b4.w};
#pragma unroll
        for (int ct = 0; ct < 4; ++ct) {
            int s = cq * 4 + ct;
            float s4[4];
#pragma unroll
            for (int r = 0; r < 4; ++r) {
                float y = acc3[rt][ct][r] + bv[r];
                y = y > 0.f ? y : 0.1f * y;
#pragma unroll
                for (int m = 1; m < 16; m <<= 1) y += __shfl_xor(y, m, 64);
                s4[r] = y;
            }
            if (lo == 0) {
                uint2 pk;
                pk.x = (unsigned int)f2bf(s4[0]) | ((unsigned int)f2bf(s4[1]) << 16);
                pk.y = (unsigned int)f2bf(s4[2]) | ((unsigned int)f2bf(s4[3]) << 16);
                *(uint2*)(pools + ((size_t)(seg0 + s) * 256 + ch0) * 2) = pk;
            }
        }
    }
}

// ---------------------------------------------------------------- K4: linear 256->256 (unchanged)
__global__ __launch_bounds__(256, 2) void k4_linear(
    const char* __restrict__ ws, const float* __restrict__ bp, float* __restrict__ out)
{
    __shared__ char ps[16384];                 // 32 segs x 256ch bf16, swizzled
    const char* pools = ws + OFF_POOL;
    const char* wpimg = ws + OFF_WP;

    const int tid = threadIdx.x, lane = tid & 63, wid = tid >> 6;
    const int seg0 = blockIdx.x * 32;
    const int hi = lane >> 4, lo = lane & 15;

#pragma unroll
    for (int is = 0; is < 4; ++is) {
        int u = wid * 256 + is * 64 + lane;    // 0..1023
        int seg = u >> 5, j = u & 31;
        gll16(pools + (size_t)(seg0 + seg) * 512 + ((j ^ (seg & 7)) * 16),
              ps + (wid * 256 + is * 64) * 16);
    }
    __syncthreads();

    f32x4 acc[4][2];
#pragma unroll
    for (int i = 0; i < 4; ++i) {
        acc[i][0] = f32x4{0.f, 0.f, 0.f, 0.f};
        acc[i][1] = f32x4{0.f, 0.f, 0.f, 0.f};
    }

#pragma unroll
    for (int q = 0; q < 8; ++q) {
        short8 bfr[2];
#pragma unroll
        for (int ct = 0; ct < 2; ++ct) {
            int seg = ct * 16 + lo;
            bfr[ct] = frag16(ps + seg * 512 + (((q * 4 + hi) ^ (seg & 7)) * 16));
        }
#pragma unroll
        for (int rt = 0; rt < 4; ++rt) {
            short8 afr = frag16(wpimg + (size_t)(((wid * 4 + rt) * 8 + q) * 64 + lane) * 16);
            acc[rt][0] = __builtin_amdgcn_mfma_f32_16x16x32_bf16(afr, bfr[0], acc[rt][0], 0, 0, 0);
            acc[rt][1] = __builtin_amdgcn_mfma_f32_16x16x32_bf16(afr, bfr[1], acc[rt][1], 0, 0, 0);
        }
    }

#pragma unroll
    for (int rt = 0; rt < 4; ++rt) {
        int ch0 = wid * 64 + rt * 16 + hi * 4;
        float4 b4 = *(const float4*)(bp + ch0);
#pragma unroll
        for (int ct = 0; ct < 2; ++ct) {
            int segl = ct * 16 + lo;
            float4 v;
            v.x = acc[rt][ct][0] + b4.x;
            v.y = acc[rt][ct][1] + b4.y;
            v.z = acc[rt][ct][2] + b4.z;
            v.w = acc[rt][ct][3] + b4.w;
            *(float4*)(out + (size_t)(seg0 + segl) * 256 + ch0) = v;
        }
    }
}

}  // namespace

extern "C" void kernel_launch(void* const* d_in, const int* in_sizes, int n_in,
                              void* d_out, int out_size, void* d_ws, size_t ws_size,
                              hipStream_t stream) {
    if (ws_size < WS_NEED) return;

    const float* imu = (const float*)d_in[0];
    const float* w1 = (const float*)d_in[1];  const float* b1 = (const float*)d_in[2];
    const float* g1 = (const float*)d_in[3];  const float* be1 = (const float*)d_in[4];
    const float* m1 = (const float*)d_in[5];  const float* v1 = (const float*)d_in[6];
    const float* w2 = (const float*)d_in[7];  const float* b2 = (const float*)d_in[8];
    const float* g2 = (const float*)d_in[9];  const float* be2 = (const float*)d_in[10];
    const float* m2 = (const float*)d_in[11]; const float* v2 = (const float*)d_in[12];
    const float* w3 = (const float*)d_in[13]; const float* b3 = (const float*)d_in[14];
    const float* g3 = (const float*)d_in[15]; const float* be3 = (const float*)d_in[16];
    const float* m3 = (const float*)d_in[17]; const float* v3 = (const float*)d_in[18];
    const float* wp = (const float*)d_in[19]; const float* bp = (const float*)d_in[20];
    float* out = (float*)d_out;
    char* ws = (char*)d_ws;

    hipFuncSetAttribute((const void*)k123_fused,
                        hipFuncAttributeMaxDynamicSharedMemorySize, LDS_TOTAL);

    hipLaunchKernelGGL(k0_prep, dim3(94), dim3(256), 0, stream,
                       w2, b2, g2, be2, m2, v2, w3, b3, g3, be3, m3, v3, wp, ws);
    hipLaunchKernelGGL(k123_fused, dim3(NSEG / 16), dim3(512), LDS_TOTAL, stream,
                       imu, w1, b1, g1, be1, m1, v1, ws);
    hipLaunchKernelGGL(k4_linear, dim3(NSEG / 32), dim3(256), 0, stream, ws, bp, out);
}

// Round 5
// 122.198 us; speedup vs baseline: 6.7853x; 1.1320x over previous
//
#include <hip/hip_runtime.h>
#include <cstdint>
#include <cstddef>

// IMUCNN1DEncoder — round 5: 2 blocks/CU, barrier-free conv3, weights L2->VGPR.
// K0:    weight prep (BN fold -> bf16 per-lane FRAGMENT-ordered panels in d_ws)
// K_all: per 8 segs (256 thr): conv1 VALU -> act1 LDS -> conv2 (A from global frags,
//        B from LDS) -> act2 LDS -> conv3 (no barriers) -> pool -> linear -> out.
// LDS: padded strides (144/272/528B) instead of swizzles -> <=2-way banks, no addr VALU.

namespace {

typedef __attribute__((ext_vector_type(8))) short short8;   // 8 bf16 = 4 VGPR
typedef __attribute__((ext_vector_type(4))) float f32x4;

constexpr int NSEG = 32 * 512;          // 16384
constexpr float kEps = 1e-5f;

// d_ws layout (bytes)
constexpr size_t OFF_A2F = 0;            // 3072 frags  * 16 = 49,152
constexpr size_t OFF_A3F = 49152;        // 12288 frags * 16 = 196,608
constexpr size_t OFF_WP  = 245760;       // 8192 frags  * 16 = 131,072
constexpr size_t OFF_B2  = 376832;       // 512
constexpr size_t OFF_B3  = 377344;       // 1024
constexpr size_t WS_NEED = 378368;

// LDS layout (static, 64,128 B -> 2 blocks/CU)
constexpr int L_ACT1 = 0;        // 8 segs * 18 rows * 144 B (128B payload + pad)
constexpr int L_ACT2 = 20736;    // 8 * 18 * 272 B (256B payload + pad)
constexpr int L_POOL = 59904;    // 8 * 528 B (512B payload + pad); imu overlays
constexpr int L_TOTAL = 64128;

__device__ __forceinline__ unsigned short f2bf(float f) {
    union { float f; unsigned int u; } a; a.f = f;
    unsigned int u = a.u + 0x7FFFu + ((a.u >> 16) & 1u);    // RNE
    return (unsigned short)(u >> 16);
}

__device__ __forceinline__ void gll16(const void* g, void* l) {
    __builtin_amdgcn_global_load_lds(
        (const __attribute__((address_space(1))) unsigned int*)g,
        (__attribute__((address_space(3))) unsigned int*)l, 16, 0, 0);
}

__device__ __forceinline__ short8 frag16(const void* p) {
    return __builtin_bit_cast(short8, *(const int4*)p);
}

// ---------------------------------------------------------------- K0: prep
// idx ranges: A2F 3072 | A3F 12288 | WP 8192 | b2 128 | b3 256  (= 23,936)
__global__ __launch_bounds__(256) void k0_prep(
    const float* __restrict__ w2, const float* __restrict__ b2, const float* __restrict__ g2,
    const float* __restrict__ be2, const float* __restrict__ m2, const float* __restrict__ v2,
    const float* __restrict__ w3, const float* __restrict__ b3, const float* __restrict__ g3,
    const float* __restrict__ be3, const float* __restrict__ m3, const float* __restrict__ v3,
    const float* __restrict__ wp, char* __restrict__ ws)
{
    int idx = blockIdx.x * 256 + threadIdx.x;
    if (idx < 3072) {                       // A2F frag f=(tap,qq,rtile[8]), elem lane
        int f = idx >> 6, lane = idx & 63;
        int tap = f >> 4, qq = (f >> 3) & 1, rtile = f & 7;
        int row = rtile * 16 + (lane & 15);
        int kb = qq * 32 + (lane >> 4) * 8;
        float a = g2[row] * rsqrtf(v2[row] + kEps);
        unsigned short us[8];
#pragma unroll
        for (int j = 0; j < 8; ++j)
            us[j] = f2bf(a * w2[row * 192 + (kb + j) * 3 + tap]);
        *(int4*)(ws + OFF_A2F + (size_t)idx * 16) = *(const int4*)us;
    } else if (idx < 15360) {               // A3F frag f=(ks[6],qq,rtile[16])
        int u = idx - 3072;
        int f = u >> 6, lane = u & 63;
        int ks = f >> 5, qq = (f >> 4) & 1, rtile = f & 15;
        int tap = ks >> 1, ih = ks & 1;
        int row = rtile * 16 + (lane & 15);
        int kb = qq * 32 + (lane >> 4) * 8;
        float a = g3[row] * rsqrtf(v3[row] + kEps);
        unsigned short us[8];
#pragma unroll
        for (int j = 0; j < 8; ++j) {
            int i = ih * 64 + kb + j;
            us[j] = f2bf(a * w3[row * 384 + i * 3 + tap]);
        }
        *(int4*)(ws + OFF_A3F + (size_t)u * 16) = *(const int4*)us;
    } else if (idx < 23552) {               // WP frags, scaled 1/16
        int u = idx - 15360;
        int f = u >> 6, lane = u & 63;
        int o = (f >> 3) * 16 + (lane & 15);
        int cb = (f & 7) * 32 + (lane >> 4) * 8;
        unsigned short us[8];
#pragma unroll
        for (int j = 0; j < 8; ++j)
            us[j] = f2bf(wp[o * 256 + cb + j] * 0.0625f);
        *(int4*)(ws + OFF_WP + (size_t)u * 16) = *(const int4*)us;
    } else if (idx < 23680) {
        int o = idx - 23552;
        float a = g2[o] * rsqrtf(v2[o] + kEps);
        ((float*)(ws + OFF_B2))[o] = a * (b2[o] - m2[o]) + be2[o];
    } else if (idx < 23936) {
        int o = idx - 23680;
        float a = g3[o] * rsqrtf(v3[o] + kEps);
        ((float*)(ws + OFF_B3))[o] = a * (b3[o] - m3[o]) + be3[o];
    }
}

// ---------------------------------------------------------------- K_all: fused pipeline
__global__ __launch_bounds__(256, 2) void k_all(
    const float* __restrict__ imu,
    const float* __restrict__ w1, const float* __restrict__ b1,
    const float* __restrict__ g1, const float* __restrict__ be1,
    const float* __restrict__ m1, const float* __restrict__ v1,
    const char* __restrict__ ws, const float* __restrict__ bp,
    float* __restrict__ out)
{
    __shared__ char smem[L_TOTAL];
    char* act1L  = smem + L_ACT1;
    char* act2L  = smem + L_ACT2;
    char* poolsL = smem + L_POOL;
    char* imuL   = poolsL;                     // imu dead before pool writes
    const char* A2F = ws + OFF_A2F;
    const char* A3F = ws + OFF_A3F;
    const char* WPF = ws + OFF_WP;
    const float* bias2 = (const float*)(ws + OFF_B2);
    const float* bias3 = (const float*)(ws + OFF_B3);

    const int tid = threadIdx.x, lane = tid & 63, wid = tid >> 6;
    const int lo = lane & 15, hi = lane >> 4;
    const int seg0 = blockIdx.x * 8;

    // ---- phase 0: imu -> LDS (3 KB)
    if (wid < 3)
        gll16((const char*)imu + (size_t)seg0 * 384 + wid * 1024 + lane * 16,
              imuL + wid * 1024);
    __syncthreads();                           // B0

    // ---- phase 1: conv1 (VALU), seg = wid and wid+4, all 64 ch per thread's c
    {
        const float* xf = (const float*)imuL;
        const int c = lane;
        const float a = g1[c] * rsqrtf(v1[c] + kEps);
        const float bb = fmaf(a, b1[c] - m1[c], be1[c]);
        float wk[6][3];
#pragma unroll
        for (int i = 0; i < 6; ++i)
#pragma unroll
            for (int k = 0; k < 3; ++k) wk[i][k] = a * w1[c * 18 + i * 3 + k];

#pragma unroll
        for (int ss = 0; ss < 2; ++ss) {
            int s = wid + ss * 4;
            float acc[16];
#pragma unroll
            for (int l = 0; l < 16; ++l) acc[l] = bb;
#pragma unroll
            for (int i = 0; i < 6; ++i) {
                float x[16];
#pragma unroll
                for (int l = 0; l < 16; ++l) x[l] = xf[s * 96 + l * 6 + i];
#pragma unroll
                for (int l = 0; l < 16; ++l) {
                    float t = wk[i][1] * x[l];
                    if (l > 0)  t = fmaf(wk[i][0], x[l - 1], t);
                    if (l < 15) t = fmaf(wk[i][2], x[l + 1], t);
                    acc[l] += t;
                }
            }
#pragma unroll
            for (int l = 0; l < 16; ++l) {
                float y = acc[l];
                y = y > 0.f ? y : 0.1f * y;
                *(unsigned short*)(act1L + (s * 18 + l + 1) * 144 + c * 2) = f2bf(y);
            }
        }
        // zero act1 halo rows (8 segs x 2 rows x 9 units)
        if (tid < 144) {
            int s = tid / 18, rest = tid % 18;
            int h = rest / 9, unit = rest % 9;
            int4 z; z.x = z.y = z.z = z.w = 0;
            *(int4*)(act1L + (s * 18 + h * 17) * 144 + unit * 16) = z;
        }
        // zero act2 halo rows (8 x 2 x 17 units = 272)
        for (int u = tid; u < 272; u += 256) {
            int s = u / 34, rest = u % 34;
            int h = rest / 17, unit = rest % 17;
            int4 z; z.x = z.y = z.z = z.w = 0;
            *(int4*)(act2L + (s * 18 + h * 17) * 272 + unit * 16) = z;
        }
    }
    __syncthreads();                           // B1: act1 ready

    // ---- phase 2: conv2  M=128 (wave owns 32 rows) x N=128 (8 segs), K=6x32
    const char* b1base = act1L + lo * 144 + hi * 16;
    f32x4 acc2[2][8];
#pragma unroll
    for (int i = 0; i < 2; ++i)
#pragma unroll
        for (int j = 0; j < 8; ++j) acc2[i][j] = f32x4{0.f, 0.f, 0.f, 0.f};
    {
        short8 a2n[2];
#pragma unroll
        for (int rt = 0; rt < 2; ++rt)
            a2n[rt] = frag16(A2F + (size_t)((0 * 8 + wid * 2 + rt) * 64 + lane) * 16);
#pragma unroll
        for (int s = 0; s < 6; ++s) {
            const int tap = s >> 1, qq = s & 1;
            short8 a2c[2]; a2c[0] = a2n[0]; a2c[1] = a2n[1];
            if (s < 5) {
#pragma unroll
                for (int rt = 0; rt < 2; ++rt)
                    a2n[rt] = frag16(A2F + (size_t)(((s + 1) * 8 + wid * 2 + rt) * 64 + lane) * 16);
            }
            short8 bfr[8];
#pragma unroll
            for (int ct = 0; ct < 8; ++ct)
                bfr[ct] = frag16(b1base + (ct * 18 + tap) * 144 + qq * 64);
#pragma unroll
            for (int rt = 0; rt < 2; ++rt)
#pragma unroll
                for (int ct = 0; ct < 8; ++ct)
                    acc2[rt][ct] = __builtin_amdgcn_mfma_f32_16x16x32_bf16(
                        a2c[rt], bfr[ct], acc2[rt][ct], 0, 0, 0);
        }
    }
    // conv2 epilogue: bias + leaky -> bf16 -> act2 LDS
#pragma unroll
    for (int rt = 0; rt < 2; ++rt) {
        int ch0 = (wid * 2 + rt) * 16 + hi * 4;
        float4 b4 = *(const float4*)(bias2 + ch0);
#pragma unroll
        for (int ct = 0; ct < 8; ++ct) {
            float y0 = acc2[rt][ct][0] + b4.x; y0 = y0 > 0.f ? y0 : 0.1f * y0;
            float y1 = acc2[rt][ct][1] + b4.y; y1 = y1 > 0.f ? y1 : 0.1f * y1;
            float y2 = acc2[rt][ct][2] + b4.z; y2 = y2 > 0.f ? y2 : 0.1f * y2;
            float y3 = acc2[rt][ct][3] + b4.w; y3 = y3 > 0.f ? y3 : 0.1f * y3;
            uint2 pk;
            pk.x = (unsigned int)f2bf(y0) | ((unsigned int)f2bf(y1) << 16);
            pk.y = (unsigned int)f2bf(y2) | ((unsigned int)f2bf(y3) << 16);
            *(uint2*)(act2L + (ct * 18 + lo + 1) * 272 + ch0 * 2) = pk;
        }
    }
    __syncthreads();                           // B2: act2 ready

    // ---- phase 3: conv3  M=256 (wave owns 64 rows) x N=128, K=12x32, NO barriers
    const char* b2base = act2L + lo * 272 + hi * 16;
    f32x4 acc3[4][8];
#pragma unroll
    for (int i = 0; i < 4; ++i)
#pragma unroll
        for (int j = 0; j < 8; ++j) acc3[i][j] = f32x4{0.f, 0.f, 0.f, 0.f};
    {
        short8 a3n[4];
#pragma unroll
        for (int rt = 0; rt < 4; ++rt)
            a3n[rt] = frag16(A3F + (size_t)((0 * 16 + wid * 4 + rt) * 64 + lane) * 16);
#pragma unroll
        for (int s = 0; s < 12; ++s) {
            const int tap = s >> 2, ih = (s >> 1) & 1, qq = s & 1;
            short8 a3c[4];
#pragma unroll
            for (int rt = 0; rt < 4; ++rt) a3c[rt] = a3n[rt];
            if (s < 11) {
#pragma unroll
                for (int rt = 0; rt < 4; ++rt)
                    a3n[rt] = frag16(A3F + (size_t)(((s + 1) * 16 + wid * 4 + rt) * 64 + lane) * 16);
            }
            short8 bfr[8];
#pragma unroll
            for (int ct = 0; ct < 8; ++ct)
                bfr[ct] = frag16(b2base + (ct * 18 + tap) * 272 + ih * 128 + qq * 64);
#pragma unroll
            for (int rt = 0; rt < 4; ++rt)
#pragma unroll
                for (int ct = 0; ct < 8; ++ct)
                    acc3[rt][ct] = __builtin_amdgcn_mfma_f32_16x16x32_bf16(
                        a3c[rt], bfr[ct], acc3[rt][ct], 0, 0, 0);
        }
    }

    // ---- phase 4: bias + leaky + pool (sum over l=lo via 16-lane xor reduce)
#pragma unroll
    for (int rt = 0; rt < 4; ++rt) {
        int ch0 = (wid * 4 + rt) * 16 + hi * 4;
        float4 b4 = *(const float4*)(bias3 + ch0);
        float bv[4] = {b4.x, b4.y, b4.z, b4.w};
#pragma unroll
        for (int ct = 0; ct < 8; ++ct) {
            float s4[4];
#pragma unroll
            for (int r = 0; r < 4; ++r) {
                float y = acc3[rt][ct][r] + bv[r];
                y = y > 0.f ? y : 0.1f * y;
#pragma unroll
                for (int m = 1; m < 16; m <<= 1) y += __shfl_xor(y, m, 64);
                s4[r] = y;
            }
            if (lo == 0) {
                uint2 pk;
                pk.x = (unsigned int)f2bf(s4[0]) | ((unsigned int)f2bf(s4[1]) << 16);
                pk.y = (unsigned int)f2bf(s4[2]) | ((unsigned int)f2bf(s4[3]) << 16);
                *(uint2*)(poolsL + ct * 528 + ch0 * 2) = pk;
            }
        }
    }
    __syncthreads();                           // B3: pools ready

    // ---- phase 5: linear 256->256 over 8 segs (cols 8-15 zeroed)
    {
        f32x4 acc4[4];
#pragma unroll
        for (int i = 0; i < 4; ++i) acc4[i] = f32x4{0.f, 0.f, 0.f, 0.f};
        const short8 z8 = {0, 0, 0, 0, 0, 0, 0, 0};
#pragma unroll
        for (int q = 0; q < 8; ++q) {
            short8 b = frag16(poolsL + (lo & 7) * 528 + q * 64 + hi * 16);
            b = (lo < 8) ? b : z8;
#pragma unroll
            for (int rt = 0; rt < 4; ++rt) {
                short8 a = frag16(WPF + (size_t)((((wid * 4 + rt) * 8 + q) * 64 + lane)) * 16);
                acc4[rt] = __builtin_amdgcn_mfma_f32_16x16x32_bf16(a, b, acc4[rt], 0, 0, 0);
            }
        }
#pragma unroll
        for (int rt = 0; rt < 4; ++rt) {
            int ch0 = (wid * 4 + rt) * 16 + hi * 4;
            if (lo < 8) {
                float4 b4 = *(const float4*)(bp + ch0);
                float4 v;
                v.x = acc4[rt][0] + b4.x;
                v.y = acc4[rt][1] + b4.y;
                v.z = acc4[rt][2] + b4.z;
                v.w = acc4[rt][3] + b4.w;
                *(float4*)(out + (size_t)(seg0 + lo) * 256 + ch0) = v;
            }
        }
    }
}

}  // namespace

extern "C" void kernel_launch(void* const* d_in, const int* in_sizes, int n_in,
                              void* d_out, int out_size, void* d_ws, size_t ws_size,
                              hipStream_t stream) {
    if (ws_size < WS_NEED) return;

    const float* imu = (const float*)d_in[0];
    const float* w1 = (const float*)d_in[1];  const float* b1 = (const float*)d_in[2];
    const float* g1 = (const float*)d_in[3];  const float* be1 = (const float*)d_in[4];
    const float* m1 = (const float*)d_in[5];  const float* v1 = (const float*)d_in[6];
    const float* w2 = (const float*)d_in[7];  const float* b2 = (const float*)d_in[8];
    const float* g2 = (const float*)d_in[9];  const float* be2 = (const float*)d_in[10];
    const float* m2 = (const float*)d_in[11]; const float* v2 = (const float*)d_in[12];
    const float* w3 = (const float*)d_in[13]; const float* b3 = (const float*)d_in[14];
    const float* g3 = (const float*)d_in[15]; const float* be3 = (const float*)d_in[16];
    const float* m3 = (const float*)d_in[17]; const float* v3 = (const float*)d_in[18];
    const float* wp = (const float*)d_in[19]; const float* bp = (const float*)d_in[20];
    float* out = (float*)d_out;
    char* ws = (char*)d_ws;

    hipLaunchKernelGGL(k0_prep, dim3(94), dim3(256), 0, stream,
                       w2, b2, g2, be2, m2, v2, w3, b3, g3, be3, m3, v3, wp, ws);
    hipLaunchKernelGGL(k_all, dim3(NSEG / 8), dim3(256), 0, stream,
                       imu, w1, b1, g1, be1, m1, v1, ws, bp, out);
}

// Round 6
// 90.915 us; speedup vs baseline: 9.1201x; 1.3441x over previous
//
#include <hip/hip_runtime.h>
#include <cstdint>
#include <cstddef>

// IMUCNN1DEncoder — round 6: 8-wave blocks (4 waves/SIMD), operand-swapped conv3
// so the pool is lane-local (+2 shfl), 2-D wave tiling to balance DS/L2 pipes.
// K0:    weight prep (BN fold -> bf16 per-lane fragment panels in d_ws)
// K_all: per 8 segs (512 thr): conv1 VALU -> act1 LDS -> conv2 (W=A global frags,
//        act=B LDS) -> act2 LDS -> conv3 SWAPPED (act=A LDS, W=B global) -> pool
//        (lane-local + 2 shfl) -> linear SWAPPED -> out.

namespace {

typedef __attribute__((ext_vector_type(8))) short short8;   // 8 bf16 = 4 VGPR
typedef __attribute__((ext_vector_type(4))) float f32x4;

constexpr int NSEG = 32 * 512;          // 16384
constexpr float kEps = 1e-5f;

// d_ws layout (bytes)
constexpr size_t OFF_A2F = 0;            // 3072 frags  * 16 = 49,152
constexpr size_t OFF_A3F = 49152;        // 12288 frags * 16 = 196,608
constexpr size_t OFF_WP  = 245760;       // 8192 frags  * 16 = 131,072
constexpr size_t OFF_B2  = 376832;       // 512
constexpr size_t OFF_B3  = 377344;       // 1024
constexpr size_t WS_NEED = 378368;

// LDS layout (static, 68,352 B -> 2 blocks/CU at 160KB)
constexpr int L_ACT2 = 20736;    // act1: 8 segs * 18 rows * 144 B = 20,736
constexpr int L_POOL = 59904;    // act2: 8 * 18 * 272 B = 39,168
constexpr int L_TOTAL = 68352;   // pools: 16 rows * 528 B = 8,448 (imu overlays)

__device__ __forceinline__ unsigned short f2bf(float f) {
    union { float f; unsigned int u; } a; a.f = f;
    unsigned int u = a.u + 0x7FFFu + ((a.u >> 16) & 1u);    // RNE
    return (unsigned short)(u >> 16);
}

__device__ __forceinline__ void gll16(const void* g, void* l) {
    __builtin_amdgcn_global_load_lds(
        (const __attribute__((address_space(1))) unsigned int*)g,
        (__attribute__((address_space(3))) unsigned int*)l, 16, 0, 0);
}

__device__ __forceinline__ short8 frag16(const void* p) {
    return __builtin_bit_cast(short8, *(const int4*)p);
}

// ---------------------------------------------------------------- K0: prep
// idx ranges: A2F 3072 | A3F 12288 | WP 8192 | b2 128 | b3 256  (= 23,936)
__global__ __launch_bounds__(256) void k0_prep(
    const float* __restrict__ w2, const float* __restrict__ b2, const float* __restrict__ g2,
    const float* __restrict__ be2, const float* __restrict__ m2, const float* __restrict__ v2,
    const float* __restrict__ w3, const float* __restrict__ b3, const float* __restrict__ g3,
    const float* __restrict__ be3, const float* __restrict__ m3, const float* __restrict__ v3,
    const float* __restrict__ wp, char* __restrict__ ws)
{
    int idx = blockIdx.x * 256 + threadIdx.x;
    if (idx < 3072) {                       // A2F frag f=(tap,qq,rtile[8]), elem lane
        int f = idx >> 6, lane = idx & 63;
        int tap = f >> 4, qq = (f >> 3) & 1, rtile = f & 7;
        int row = rtile * 16 + (lane & 15);
        int kb = qq * 32 + (lane >> 4) * 8;
        float a = g2[row] * rsqrtf(v2[row] + kEps);
        unsigned short us[8];
#pragma unroll
        for (int j = 0; j < 8; ++j)
            us[j] = f2bf(a * w2[row * 192 + (kb + j) * 3 + tap]);
        *(int4*)(ws + OFF_A2F + (size_t)idx * 16) = *(const int4*)us;
    } else if (idx < 15360) {               // A3F frag f=(ks[6],qq,rtile[16])
        int u = idx - 3072;
        int f = u >> 6, lane = u & 63;
        int ks = f >> 5, qq = (f >> 4) & 1, rtile = f & 15;
        int tap = ks >> 1, ih = ks & 1;
        int row = rtile * 16 + (lane & 15);
        int kb = qq * 32 + (lane >> 4) * 8;
        float a = g3[row] * rsqrtf(v3[row] + kEps);
        unsigned short us[8];
#pragma unroll
        for (int j = 0; j < 8; ++j) {
            int i = ih * 64 + kb + j;
            us[j] = f2bf(a * w3[row * 384 + i * 3 + tap]);
        }
        *(int4*)(ws + OFF_A3F + (size_t)u * 16) = *(const int4*)us;
    } else if (idx < 23552) {               // WP frags, scaled 1/16
        int u = idx - 15360;
        int f = u >> 6, lane = u & 63;
        int o = (f >> 3) * 16 + (lane & 15);
        int cb = (f & 7) * 32 + (lane >> 4) * 8;
        unsigned short us[8];
#pragma unroll
        for (int j = 0; j < 8; ++j)
            us[j] = f2bf(wp[o * 256 + cb + j] * 0.0625f);
        *(int4*)(ws + OFF_WP + (size_t)u * 16) = *(const int4*)us;
    } else if (idx < 23680) {
        int o = idx - 23552;
        float a = g2[o] * rsqrtf(v2[o] + kEps);
        ((float*)(ws + OFF_B2))[o] = a * (b2[o] - m2[o]) + be2[o];
    } else if (idx < 23936) {
        int o = idx - 23680;
        float a = g3[o] * rsqrtf(v3[o] + kEps);
        ((float*)(ws + OFF_B3))[o] = a * (b3[o] - m3[o]) + be3[o];
    }
}

// ---------------------------------------------------------------- K_all: fused pipeline
__global__ __launch_bounds__(512, 4) void k_all(
    const float* __restrict__ imu,
    const float* __restrict__ w1, const float* __restrict__ b1,
    const float* __restrict__ g1, const float* __restrict__ be1,
    const float* __restrict__ m1, const float* __restrict__ v1,
    const char* __restrict__ ws, const float* __restrict__ bp,
    float* __restrict__ out)
{
    __shared__ char smem[L_TOTAL];
    char* act1L  = smem;
    char* act2L  = smem + L_ACT2;
    char* poolsL = smem + L_POOL;
    char* imuL   = poolsL;                     // imu dead after conv1 (pre-B1)
    const char* A2F = ws + OFF_A2F;
    const char* A3F = ws + OFF_A3F;
    const char* WPF = ws + OFF_WP;
    const float* bias2 = (const float*)(ws + OFF_B2);
    const float* bias3 = (const float*)(ws + OFF_B3);

    const int tid = threadIdx.x, lane = tid & 63, wid = tid >> 6;  // wid 0..7
    const int lo = lane & 15, hi = lane >> 4;
    const int seg0 = blockIdx.x * 8;

    // ---- phase 0: imu -> LDS (3 KB)
    if (wid < 3)
        gll16((const char*)imu + (size_t)seg0 * 384 + wid * 1024 + lane * 16,
              imuL + wid * 1024);
    __syncthreads();                           // B0

    // ---- phase 1: conv1 (VALU), wave wid -> seg wid, thread c = lane
    {
        const float* xf = (const float*)imuL;
        const int c = lane;
        const float a = g1[c] * rsqrtf(v1[c] + kEps);
        const float bb = fmaf(a, b1[c] - m1[c], be1[c]);
        float wk[6][3];
#pragma unroll
        for (int i = 0; i < 6; ++i)
#pragma unroll
            for (int k = 0; k < 3; ++k) wk[i][k] = a * w1[c * 18 + i * 3 + k];

        float acc[16];
#pragma unroll
        for (int l = 0; l < 16; ++l) acc[l] = bb;
#pragma unroll
        for (int i = 0; i < 6; ++i) {
            float x[16];
#pragma unroll
            for (int l = 0; l < 16; ++l) x[l] = xf[wid * 96 + l * 6 + i];
#pragma unroll
            for (int l = 0; l < 16; ++l) {
                float t = wk[i][1] * x[l];
                if (l > 0)  t = fmaf(wk[i][0], x[l - 1], t);
                if (l < 15) t = fmaf(wk[i][2], x[l + 1], t);
                acc[l] += t;
            }
        }
#pragma unroll
        for (int l = 0; l < 16; ++l) {
            float y = acc[l];
            y = y > 0.f ? y : 0.1f * y;
            *(unsigned short*)(act1L + (wid * 18 + l + 1) * 144 + c * 2) = f2bf(y);
        }
        // zero act1 halo rows (8 segs x 2 rows x 9 units)
        if (tid < 144) {
            int s = tid / 18, rest = tid % 18;
            int h = rest / 9, unit = rest % 9;
            int4 z; z.x = z.y = z.z = z.w = 0;
            *(int4*)(act1L + (s * 18 + h * 17) * 144 + unit * 16) = z;
        }
        // zero act2 halo rows (8 x 2 x 17 units = 272)
        if (tid < 272) {
            int s = tid / 34, rest = tid % 34;
            int h = rest / 17, unit = rest % 17;
            int4 z; z.x = z.y = z.z = z.w = 0;
            *(int4*)(act2L + (s * 18 + h * 17) * 272 + unit * 16) = z;
        }
    }
    __syncthreads();                           // B1: act1 ready

    // ---- phase 2: conv2 (W as A from global frags, act1 as B from LDS)
    //      wave (mi = wid>>1, ni = wid&1): rows [mi*32,+32), cols [ni*64,+64)
    {
        const int mi = wid >> 1, ni = wid & 1;
        const char* b1base = act1L + lo * 144 + hi * 16;
        f32x4 acc2[2][4];
#pragma unroll
        for (int i = 0; i < 2; ++i)
#pragma unroll
            for (int j = 0; j < 4; ++j) acc2[i][j] = f32x4{0.f, 0.f, 0.f, 0.f};

        short8 a2n[2];
#pragma unroll
        for (int rt = 0; rt < 2; ++rt)
            a2n[rt] = frag16(A2F + (size_t)((mi * 2 + rt) * 64 + lane) * 16);
#pragma unroll
        for (int s = 0; s < 6; ++s) {
            const int tap = s >> 1, qq = s & 1;
            short8 a2c[2]; a2c[0] = a2n[0]; a2c[1] = a2n[1];
            if (s < 5) {
#pragma unroll
                for (int rt = 0; rt < 2; ++rt)
                    a2n[rt] = frag16(A2F + (size_t)(((s + 1) * 8 + mi * 2 + rt) * 64 + lane) * 16);
            }
#pragma unroll
            for (int ct = 0; ct < 4; ++ct) {
                short8 bfr = frag16(b1base + ((ni * 4 + ct) * 18 + tap) * 144 + qq * 64);
                acc2[0][ct] = __builtin_amdgcn_mfma_f32_16x16x32_bf16(a2c[0], bfr, acc2[0][ct], 0, 0, 0);
                acc2[1][ct] = __builtin_amdgcn_mfma_f32_16x16x32_bf16(a2c[1], bfr, acc2[1][ct], 0, 0, 0);
            }
        }
        // epilogue: bias + leaky -> bf16 -> act2 LDS (C: row=cout, col=seg*l)
#pragma unroll
        for (int rt = 0; rt < 2; ++rt) {
            int ch0 = (mi * 2 + rt) * 16 + hi * 4;
            float4 b4 = *(const float4*)(bias2 + ch0);
#pragma unroll
            for (int ct = 0; ct < 4; ++ct) {
                float y0 = acc2[rt][ct][0] + b4.x; y0 = y0 > 0.f ? y0 : 0.1f * y0;
                float y1 = acc2[rt][ct][1] + b4.y; y1 = y1 > 0.f ? y1 : 0.1f * y1;
                float y2 = acc2[rt][ct][2] + b4.z; y2 = y2 > 0.f ? y2 : 0.1f * y2;
                float y3 = acc2[rt][ct][3] + b4.w; y3 = y3 > 0.f ? y3 : 0.1f * y3;
                uint2 pk;
                pk.x = (unsigned int)f2bf(y0) | ((unsigned int)f2bf(y1) << 16);
                pk.y = (unsigned int)f2bf(y2) | ((unsigned int)f2bf(y3) << 16);
                *(uint2*)(act2L + ((ni * 4 + ct) * 18 + lo + 1) * 272 + ch0 * 2) = pk;
            }
        }
        // zero pools pad rows 8..15 (8 rows x 33 int4 = 264; imu dead since B1)
        if (tid < 264) {
            int row = 8 + tid / 33, unit = tid % 33;
            int4 z; z.x = z.y = z.z = z.w = 0;
            *(int4*)(poolsL + row * 528 + unit * 16) = z;
        }
    }
    __syncthreads();                           // B2: act2 ready

    // ---- phase 3: conv3 SWAPPED (act2 as A from LDS, W as B from global frags)
    //      wave (ni = wid>>1: couts [ni*64,+64), mi = wid&1: segs [mi*4,+4))
    {
        const int ni = wid >> 1, mi = wid & 1;
        f32x4 acc3[4][4];                      // [mt][ct]
#pragma unroll
        for (int i = 0; i < 4; ++i)
#pragma unroll
            for (int j = 0; j < 4; ++j) acc3[i][j] = f32x4{0.f, 0.f, 0.f, 0.f};

        short8 w3n[4];
#pragma unroll
        for (int ct = 0; ct < 4; ++ct)
            w3n[ct] = frag16(A3F + (size_t)((ni * 4 + ct) * 64 + lane) * 16);
#pragma unroll
        for (int s = 0; s < 12; ++s) {
            const int tap = s >> 2, ih = (s >> 1) & 1, qq = s & 1;
            short8 w3c[4];
#pragma unroll
            for (int ct = 0; ct < 4; ++ct) w3c[ct] = w3n[ct];
            if (s < 11) {
#pragma unroll
                for (int ct = 0; ct < 4; ++ct)
                    w3n[ct] = frag16(A3F + (size_t)(((s + 1) * 16 + ni * 4 + ct) * 64 + lane) * 16);
            }
#pragma unroll
            for (int mt = 0; mt < 4; ++mt) {
                short8 afr = frag16(act2L + ((mi * 4 + mt) * 18 + lo + tap) * 272
                                    + ih * 128 + qq * 64 + hi * 16);
#pragma unroll
                for (int ct = 0; ct < 4; ++ct)
                    acc3[mt][ct] = __builtin_amdgcn_mfma_f32_16x16x32_bf16(
                        afr, w3c[ct], acc3[mt][ct], 0, 0, 0);
            }
        }

        // ---- phase 4: pool. C: row = l (hi*4+r), col = cout (lo). Sum over l:
        //      3 lane-local adds + shfl_xor(16) + shfl_xor(32).
#pragma unroll
        for (int ct = 0; ct < 4; ++ct) {
            int co = (ni * 4 + ct) * 16 + lo;
            float bv = bias3[co];
#pragma unroll
            for (int mt = 0; mt < 4; ++mt) {
                float t = 0.f;
#pragma unroll
                for (int r = 0; r < 4; ++r) {
                    float y = acc3[mt][ct][r] + bv;
                    y = y > 0.f ? y : 0.1f * y;
                    t += y;
                }
                t += __shfl_xor(t, 16, 64);
                t += __shfl_xor(t, 32, 64);
                if (hi == 0)
                    *(unsigned short*)(poolsL + (mi * 4 + mt) * 528 + co * 2) = f2bf(t);
            }
        }
    }
    __syncthreads();                           // B3: pools ready

    // ---- phase 5: linear SWAPPED (pools as A, WP as B). C: row=seg, col=o.
    {
        f32x4 acc4[2];
        acc4[0] = f32x4{0.f, 0.f, 0.f, 0.f};
        acc4[1] = f32x4{0.f, 0.f, 0.f, 0.f};
#pragma unroll
        for (int q = 0; q < 8; ++q) {
            short8 pa = frag16(poolsL + lo * 528 + q * 64 + hi * 16);
#pragma unroll
            for (int ct = 0; ct < 2; ++ct) {
                short8 wb = frag16(WPF + (size_t)(((wid * 2 + ct) * 8 + q) * 64 + lane) * 16);
                acc4[ct] = __builtin_amdgcn_mfma_f32_16x16x32_bf16(pa, wb, acc4[ct], 0, 0, 0);
            }
        }
        if (hi < 2) {
#pragma unroll
            for (int ct = 0; ct < 2; ++ct) {
                int o = (wid * 2 + ct) * 16 + lo;
                float bv = bp[o];
#pragma unroll
                for (int r = 0; r < 4; ++r)
                    out[(size_t)(seg0 + hi * 4 + r) * 256 + o] = acc4[ct][r] + bv;
            }
        }
    }
}

}  // namespace

extern "C" void kernel_launch(void* const* d_in, const int* in_sizes, int n_in,
                              void* d_out, int out_size, void* d_ws, size_t ws_size,
                              hipStream_t stream) {
    if (ws_size < WS_NEED) return;

    const float* imu = (const float*)d_in[0];
    const float* w1 = (const float*)d_in[1];  const float* b1 = (const float*)d_in[2];
    const float* g1 = (const float*)d_in[3];  const float* be1 = (const float*)d_in[4];
    const float* m1 = (const float*)d_in[5];  const float* v1 = (const float*)d_in[6];
    const float* w2 = (const float*)d_in[7];  const float* b2 = (const float*)d_in[8];
    const float* g2 = (const float*)d_in[9];  const float* be2 = (const float*)d_in[10];
    const float* m2 = (const float*)d_in[11]; const float* v2 = (const float*)d_in[12];
    const float* w3 = (const float*)d_in[13]; const float* b3 = (const float*)d_in[14];
    const float* g3 = (const float*)d_in[15]; const float* be3 = (const float*)d_in[16];
    const float* m3 = (const float*)d_in[17]; const float* v3 = (const float*)d_in[18];
    const float* wp = (const float*)d_in[19]; const float* bp = (const float*)d_in[20];
    float* out = (float*)d_out;
    char* ws = (char*)d_ws;

    hipLaunchKernelGGL(k0_prep, dim3(94), dim3(256), 0, stream,
                       w2, b2, g2, be2, m2, v2, w3, b3, g3, be3, m3, v3, wp, ws);
    hipLaunchKernelGGL(k_all, dim3(NSEG / 8), dim3(512), 0, stream,
                       imu, w1, b1, g1, be1, m1, v1, ws, bp, out);
}

// Round 7
// 85.863 us; speedup vs baseline: 9.6568x; 1.0588x over previous
//
#include <hip/hip_runtime.h>
#include <cstdint>
#include <cstddef>

// IMUCNN1DEncoder — round 7: raw barriers (no vmcnt drain) + cross-barrier weight
// prefetch (2-deep), split-bf16 pools (precision), per-l conv1, fmax leaky, setprio.
// K0:    weight prep (BN fold -> bf16 per-lane fragment panels in d_ws)
// K_all: per 8 segs (512 thr): conv1 VALU -> act1 LDS -> conv2 (W=A prefetched regs,
//        act=B LDS) -> act2 LDS -> conv3 SWAPPED (act=A LDS, W=B prefetched regs)
//        -> pool (lane-local + 2 shfl, hi/lo bf16 planes) -> linear -> out.

namespace {

typedef __attribute__((ext_vector_type(8))) short short8;   // 8 bf16 = 4 VGPR
typedef __attribute__((ext_vector_type(4))) float f32x4;

constexpr int NSEG = 32 * 512;          // 16384
constexpr float kEps = 1e-5f;

// d_ws layout (bytes)
constexpr size_t OFF_A2F = 0;            // 3072 frags  * 16 = 49,152
constexpr size_t OFF_A3F = 49152;        // 12288 frags * 16 = 196,608
constexpr size_t OFF_WP  = 245760;       // 8192 frags  * 16 = 131,072
constexpr size_t OFF_B2  = 376832;       // 512
constexpr size_t OFF_B3  = 377344;       // 1024
constexpr size_t WS_NEED = 378368;

// LDS layout (static, 68,352 B -> 2 blocks/CU at 160KB)
constexpr int L_ACT2 = 20736;    // act1: 8 segs * 18 rows * 144 B = 20,736
constexpr int L_POOL = 59904;    // act2: 8 * 18 * 272 B = 39,168
constexpr int L_TOTAL = 68352;   // pools: 16 rows * 528 B (rows 0-7 hi, 8-15 lo)

__device__ __forceinline__ unsigned short f2bf(float f) {
    union { float f; unsigned int u; } a; a.f = f;
    unsigned int u = a.u + 0x7FFFu + ((a.u >> 16) & 1u);    // RNE
    return (unsigned short)(u >> 16);
}
__device__ __forceinline__ float bf2f(unsigned short h) {
    union { unsigned int u; float f; } a; a.u = ((unsigned int)h) << 16;
    return a.f;
}

__device__ __forceinline__ void gll16(const void* g, void* l) {
    __builtin_amdgcn_global_load_lds(
        (const __attribute__((address_space(1))) unsigned int*)g,
        (__attribute__((address_space(3))) unsigned int*)l, 16, 0, 0);
}

__device__ __forceinline__ short8 frag16(const void* p) {
    return __builtin_bit_cast(short8, *(const int4*)p);
}

// m201-family raw barrier: drain LDS ops only; vmcnt (VGPR prefetches) survives.
__device__ __forceinline__ void sync_lds() {
    asm volatile("s_waitcnt lgkmcnt(0)" ::: "memory");
    __builtin_amdgcn_s_barrier();
    asm volatile("" ::: "memory");
    __builtin_amdgcn_sched_barrier(0);
}
__device__ __forceinline__ void sync_vm_lds() {   // for gll16-staged data
    asm volatile("s_waitcnt vmcnt(0) lgkmcnt(0)" ::: "memory");
    __builtin_amdgcn_s_barrier();
    asm volatile("" ::: "memory");
    __builtin_amdgcn_sched_barrier(0);
}

__device__ __forceinline__ float leaky(float y) { return fmaxf(y, 0.1f * y); }

// ---------------------------------------------------------------- K0: prep
// idx ranges: A2F 3072 | A3F 12288 | WP 8192 | b2 128 | b3 256  (= 23,936)
__global__ __launch_bounds__(256) void k0_prep(
    const float* __restrict__ w2, const float* __restrict__ b2, const float* __restrict__ g2,
    const float* __restrict__ be2, const float* __restrict__ m2, const float* __restrict__ v2,
    const float* __restrict__ w3, const float* __restrict__ b3, const float* __restrict__ g3,
    const float* __restrict__ be3, const float* __restrict__ m3, const float* __restrict__ v3,
    const float* __restrict__ wp, char* __restrict__ ws)
{
    int idx = blockIdx.x * 256 + threadIdx.x;
    if (idx < 3072) {                       // A2F frag f=(tap,qq,rtile[8]), elem lane
        int f = idx >> 6, lane = idx & 63;
        int tap = f >> 4, qq = (f >> 3) & 1, rtile = f & 7;
        int row = rtile * 16 + (lane & 15);
        int kb = qq * 32 + (lane >> 4) * 8;
        float a = g2[row] * rsqrtf(v2[row] + kEps);
        unsigned short us[8];
#pragma unroll
        for (int j = 0; j < 8; ++j)
            us[j] = f2bf(a * w2[row * 192 + (kb + j) * 3 + tap]);
        *(int4*)(ws + OFF_A2F + (size_t)idx * 16) = *(const int4*)us;
    } else if (idx < 15360) {               // A3F frag f=(ks[6],qq,rtile[16])
        int u = idx - 3072;
        int f = u >> 6, lane = u & 63;
        int ks = f >> 5, qq = (f >> 4) & 1, rtile = f & 15;
        int tap = ks >> 1, ih = ks & 1;
        int row = rtile * 16 + (lane & 15);
        int kb = qq * 32 + (lane >> 4) * 8;
        float a = g3[row] * rsqrtf(v3[row] + kEps);
        unsigned short us[8];
#pragma unroll
        for (int j = 0; j < 8; ++j) {
            int i = ih * 64 + kb + j;
            us[j] = f2bf(a * w3[row * 384 + i * 3 + tap]);
        }
        *(int4*)(ws + OFF_A3F + (size_t)u * 16) = *(const int4*)us;
    } else if (idx < 23552) {               // WP frags, scaled 1/16
        int u = idx - 15360;
        int f = u >> 6, lane = u & 63;
        int o = (f >> 3) * 16 + (lane & 15);
        int cb = (f & 7) * 32 + (lane >> 4) * 8;
        unsigned short us[8];
#pragma unroll
        for (int j = 0; j < 8; ++j)
            us[j] = f2bf(wp[o * 256 + cb + j] * 0.0625f);
        *(int4*)(ws + OFF_WP + (size_t)u * 16) = *(const int4*)us;
    } else if (idx < 23680) {
        int o = idx - 23552;
        float a = g2[o] * rsqrtf(v2[o] + kEps);
        ((float*)(ws + OFF_B2))[o] = a * (b2[o] - m2[o]) + be2[o];
    } else if (idx < 23936) {
        int o = idx - 23680;
        float a = g3[o] * rsqrtf(v3[o] + kEps);
        ((float*)(ws + OFF_B3))[o] = a * (b3[o] - m3[o]) + be3[o];
    }
}

// ---------------------------------------------------------------- K_all: fused pipeline
__global__ __launch_bounds__(512, 4) void k_all(
    const float* __restrict__ imu,
    const float* __restrict__ w1, const float* __restrict__ b1,
    const float* __restrict__ g1, const float* __restrict__ be1,
    const float* __restrict__ m1, const float* __restrict__ v1,
    const char* __restrict__ ws, const float* __restrict__ bp,
    float* __restrict__ out)
{
    __shared__ char smem[L_TOTAL];
    char* act1L  = smem;
    char* act2L  = smem + L_ACT2;
    char* poolsL = smem + L_POOL;
    char* imuL   = poolsL;                     // imu dead before pool writes
    const char* A2F = ws + OFF_A2F;
    const char* A3F = ws + OFF_A3F;
    const char* WPF = ws + OFF_WP;
    const float* bias2 = (const float*)(ws + OFF_B2);
    const float* bias3 = (const float*)(ws + OFF_B3);

    const int tid = threadIdx.x, lane = tid & 63, wid = tid >> 6;  // wid 0..7
    const int lo = lane & 15, hi = lane >> 4;
    const int seg0 = blockIdx.x * 8;

    // ---- phase 0: imu -> LDS (3 KB)
    if (wid < 3)
        gll16((const char*)imu + (size_t)seg0 * 384 + wid * 1024 + lane * 16,
              imuL + wid * 1024);
    sync_vm_lds();                             // B0

    // ---- phase 1: conv1 (VALU), wave wid -> seg wid, thread c = lane
    {
        const float* xr = (const float*)imuL + wid * 96;
        const int c = lane;
        const float a = g1[c] * rsqrtf(v1[c] + kEps);
        const float bb = fmaf(a, b1[c] - m1[c], be1[c]);
        float wk[6][3];
#pragma unroll
        for (int i = 0; i < 6; ++i)
#pragma unroll
            for (int k = 0; k < 3; ++k) wk[i][k] = a * w1[c * 18 + i * 3 + k];

        float acc[16];
#pragma unroll
        for (int l = 0; l < 16; ++l) acc[l] = bb;
#pragma unroll
        for (int l = 0; l < 16; ++l) {
            float2 c01 = *(const float2*)(xr + l * 6);
            float2 c23 = *(const float2*)(xr + l * 6 + 2);
            float2 c45 = *(const float2*)(xr + l * 6 + 4);
            float xs6[6] = {c01.x, c01.y, c23.x, c23.y, c45.x, c45.y};
#pragma unroll
            for (int i = 0; i < 6; ++i) {
                float xv = xs6[i];
                if (l > 0)  acc[l - 1] = fmaf(wk[i][2], xv, acc[l - 1]);
                acc[l] = fmaf(wk[i][1], xv, acc[l]);
                if (l < 15) acc[l + 1] = fmaf(wk[i][0], xv, acc[l + 1]);
            }
        }
#pragma unroll
        for (int l = 0; l < 16; ++l)
            *(unsigned short*)(act1L + (wid * 18 + l + 1) * 144 + c * 2) = f2bf(leaky(acc[l]));
        // zero act1 halo rows (8 segs x 2 rows x 9 units)
        if (tid < 144) {
            int s = tid / 18, rest = tid % 18;
            int h = rest / 9, unit = rest % 9;
            int4 z; z.x = z.y = z.z = z.w = 0;
            *(int4*)(act1L + (s * 18 + h * 17) * 144 + unit * 16) = z;
        }
        // zero act2 halo rows (8 x 2 x 17 units = 272)
        if (tid < 272) {
            int s = tid / 34, rest = tid % 34;
            int h = rest / 17, unit = rest % 17;
            int4 z; z.x = z.y = z.z = z.w = 0;
            *(int4*)(act2L + (s * 18 + h * 17) * 272 + unit * 16) = z;
        }
    }

    // ---- conv2 weight prefetch (s=0,1) issued BEFORE B1; vmcnt not drained there
    const int mi2 = wid >> 1, ni2 = wid & 1;
    short8 a2p[2][2];
#pragma unroll
    for (int s = 0; s < 2; ++s)
#pragma unroll
        for (int rt = 0; rt < 2; ++rt)
            a2p[s][rt] = frag16(A2F + (size_t)((s * 8 + mi2 * 2 + rt) * 64 + lane) * 16);

    sync_lds();                                // B1: act1 ready

    // ---- phase 2: conv2 (W as A from prefetched regs, act1 as B from LDS)
    //      wave (mi2, ni2): rows [mi2*32,+32), cols [ni2*64,+64)
    f32x4 acc2[2][4];
#pragma unroll
    for (int i = 0; i < 2; ++i)
#pragma unroll
        for (int j = 0; j < 4; ++j) acc2[i][j] = f32x4{0.f, 0.f, 0.f, 0.f};
    {
        const char* b1base = act1L + lo * 144 + hi * 16;
#pragma unroll
        for (int s = 0; s < 6; ++s) {
            const int tap = s >> 1, qq = s & 1;
            short8 bfr[4];
#pragma unroll
            for (int ct = 0; ct < 4; ++ct)
                bfr[ct] = frag16(b1base + ((ni2 * 4 + ct) * 18 + tap) * 144 + qq * 64);
            __builtin_amdgcn_s_setprio(1);
#pragma unroll
            for (int ct = 0; ct < 4; ++ct) {
                acc2[0][ct] = __builtin_amdgcn_mfma_f32_16x16x32_bf16(a2p[s & 1][0], bfr[ct], acc2[0][ct], 0, 0, 0);
                acc2[1][ct] = __builtin_amdgcn_mfma_f32_16x16x32_bf16(a2p[s & 1][1], bfr[ct], acc2[1][ct], 0, 0, 0);
            }
            __builtin_amdgcn_s_setprio(0);
            if (s < 4) {
#pragma unroll
                for (int rt = 0; rt < 2; ++rt)
                    a2p[s & 1][rt] = frag16(A2F + (size_t)(((s + 2) * 8 + mi2 * 2 + rt) * 64 + lane) * 16);
            }
        }
    }

    // ---- conv3 weight prefetch (s=0,1) issued BEFORE B2 (under conv2 epilogue)
    const int ni3 = wid >> 1, mi3 = wid & 1;
    short8 w3p[2][4];
#pragma unroll
    for (int s = 0; s < 2; ++s)
#pragma unroll
        for (int ct = 0; ct < 4; ++ct)
            w3p[s][ct] = frag16(A3F + (size_t)((s * 16 + ni3 * 4 + ct) * 64 + lane) * 16);

    // conv2 epilogue: bias + leaky -> bf16 -> act2 LDS (row=(seg,l), col=cout)
#pragma unroll
    for (int rt = 0; rt < 2; ++rt) {
        int ch0 = (mi2 * 2 + rt) * 16 + hi * 4;
        float4 b4 = *(const float4*)(bias2 + ch0);
#pragma unroll
        for (int ct = 0; ct < 4; ++ct) {
            float y0 = leaky(acc2[rt][ct][0] + b4.x);
            float y1 = leaky(acc2[rt][ct][1] + b4.y);
            float y2 = leaky(acc2[rt][ct][2] + b4.z);
            float y3 = leaky(acc2[rt][ct][3] + b4.w);
            uint2 pk;
            pk.x = (unsigned int)f2bf(y0) | ((unsigned int)f2bf(y1) << 16);
            pk.y = (unsigned int)f2bf(y2) | ((unsigned int)f2bf(y3) << 16);
            *(uint2*)(act2L + ((ni2 * 4 + ct) * 18 + lo + 1) * 272 + ch0 * 2) = pk;
        }
    }
    sync_lds();                                // B2: act2 ready

    // ---- phase 3: conv3 SWAPPED (act2 as A from LDS, W as B from prefetched regs)
    //      wave (ni3: couts [ni3*64,+64), mi3: segs [mi3*4,+4))
    f32x4 acc3[4][4];                          // [mt][ct]
#pragma unroll
    for (int i = 0; i < 4; ++i)
#pragma unroll
        for (int j = 0; j < 4; ++j) acc3[i][j] = f32x4{0.f, 0.f, 0.f, 0.f};
    {
#pragma unroll
        for (int s = 0; s < 12; ++s) {
            const int tap = s >> 2, ih = (s >> 1) & 1, qq = s & 1;
            short8 afr[4];
#pragma unroll
            for (int mt = 0; mt < 4; ++mt)
                afr[mt] = frag16(act2L + ((mi3 * 4 + mt) * 18 + lo + tap) * 272
                                 + ih * 128 + qq * 64 + hi * 16);
            __builtin_amdgcn_s_setprio(1);
#pragma unroll
            for (int mt = 0; mt < 4; ++mt)
#pragma unroll
                for (int ct = 0; ct < 4; ++ct)
                    acc3[mt][ct] = __builtin_amdgcn_mfma_f32_16x16x32_bf16(
                        afr[mt], w3p[s & 1][ct], acc3[mt][ct], 0, 0, 0);
            __builtin_amdgcn_s_setprio(0);
            if (s < 10) {
#pragma unroll
                for (int ct = 0; ct < 4; ++ct)
                    w3p[s & 1][ct] = frag16(A3F + (size_t)(((s + 2) * 16 + ni3 * 4 + ct) * 64 + lane) * 16);
            }
        }
    }

    // ---- phase 4: pool. C: row = l (hi*4+r), col = cout (lo).
    //      Sum over l: 4 lane-local + shfl 16 + shfl 32; store hi/lo bf16 planes.
#pragma unroll
    for (int ct = 0; ct < 4; ++ct) {
        int co = (ni3 * 4 + ct) * 16 + lo;
        float bv = bias3[co];
#pragma unroll
        for (int mt = 0; mt < 4; ++mt) {
            float t = 0.f;
#pragma unroll
            for (int r = 0; r < 4; ++r)
                t += leaky(acc3[mt][ct][r] + bv);
            t += __shfl_xor(t, 16, 64);
            t += __shfl_xor(t, 32, 64);
            if (hi == 0) {
                unsigned short ph = f2bf(t);
                unsigned short pl = f2bf(t - bf2f(ph));
                int row = mi3 * 4 + mt;
                *(unsigned short*)(poolsL + row * 528 + co * 2) = ph;
                *(unsigned short*)(poolsL + (row + 8) * 528 + co * 2) = pl;
            }
        }
    }

    // ---- linear weight prefetch (q=0,1) issued BEFORE B3
    short8 wbp[2][2];
#pragma unroll
    for (int q = 0; q < 2; ++q)
#pragma unroll
        for (int ct = 0; ct < 2; ++ct)
            wbp[q][ct] = frag16(WPF + (size_t)(((wid * 2 + ct) * 8 + q) * 64 + lane) * 16);

    sync_lds();                                // B3: pools ready

    // ---- phase 5: linear (pools [hi;lo] as A rows 0..15, WP as B). C row s + row s+8.
    {
        f32x4 acc4[2];
        acc4[0] = f32x4{0.f, 0.f, 0.f, 0.f};
        acc4[1] = f32x4{0.f, 0.f, 0.f, 0.f};
#pragma unroll
        for (int q = 0; q < 8; ++q) {
            short8 pa = frag16(poolsL + lo * 528 + q * 64 + hi * 16);
            acc4[0] = __builtin_amdgcn_mfma_f32_16x16x32_bf16(pa, wbp[q & 1][0], acc4[0], 0, 0, 0);
            acc4[1] = __builtin_amdgcn_mfma_f32_16x16x32_bf16(pa, wbp[q & 1][1], acc4[1], 0, 0, 0);
            if (q < 6) {
#pragma unroll
                for (int ct = 0; ct < 2; ++ct)
                    wbp[q & 1][ct] = frag16(WPF + (size_t)(((wid * 2 + ct) * 8 + q + 2) * 64 + lane) * 16);
            }
        }
#pragma unroll
        for (int ct = 0; ct < 2; ++ct) {
            int o = (wid * 2 + ct) * 16 + lo;
            float bv = bp[o];
#pragma unroll
            for (int r = 0; r < 4; ++r) {
                float t = acc4[ct][r] + __shfl_xor(acc4[ct][r], 32, 64);
                if (hi < 2)
                    out[(size_t)(seg0 + hi * 4 + r) * 256 + o] = t + bv;
            }
        }
    }
}

}  // namespace

extern "C" void kernel_launch(void* const* d_in, const int* in_sizes, int n_in,
                              void* d_out, int out_size, void* d_ws, size_t ws_size,
                              hipStream_t stream) {
    if (ws_size < WS_NEED) return;

    const float* imu = (const float*)d_in[0];
    const float* w1 = (const float*)d_in[1];  const float* b1 = (const float*)d_in[2];
    const float* g1 = (const float*)d_in[3];  const float* be1 = (const float*)d_in[4];
    const float* m1 = (const float*)d_in[5];  const float* v1 = (const float*)d_in[6];
    const float* w2 = (const float*)d_in[7];  const float* b2 = (const float*)d_in[8];
    const float* g2 = (const float*)d_in[9];  const float* be2 = (const float*)d_in[10];
    const float* m2 = (const float*)d_in[11]; const float* v2 = (const float*)d_in[12];
    const float* w3 = (const float*)d_in[13]; const float* b3 = (const float*)d_in[14];
    const float* g3 = (const float*)d_in[15]; const float* be3 = (const float*)d_in[16];
    const float* m3 = (const float*)d_in[17]; const float* v3 = (const float*)d_in[18];
    const float* wp = (const float*)d_in[19]; const float* bp = (const float*)d_in[20];
    float* out = (float*)d_out;
    char* ws = (char*)d_ws;

    hipLaunchKernelGGL(k0_prep, dim3(94), dim3(256), 0, stream,
                       w2, b2, g2, be2, m2, v2, w3, b3, g3, be3, m3, v3, wp, ws);
    hipLaunchKernelGGL(k_all, dim3(NSEG / 8), dim3(512), 0, stream,
                       imu, w1, b1, g1, be1, m1, v1, ws, bp, out);
}